// Round 10
// baseline (673.140 us; speedup 1.0000x reference)
//
#include <hip/hip_runtime.h>

typedef unsigned short u16;
typedef __attribute__((ext_vector_type(8))) short bhalf8;   // 8 bf16 in 4 VGPRs
typedef __attribute__((ext_vector_type(4))) float floatx4;

// ---------------- helpers ----------------
__device__ __forceinline__ u16 f2bf(float f) {
    union { float f; unsigned u; } v; v.f = f;
    unsigned u = v.u;
    unsigned r = u + 0x7fffu + ((u >> 16) & 1u);
    return (u16)(r >> 16);
}
__device__ __forceinline__ float b2f(u16 h) {
    union { unsigned u; float f; } v; v.u = ((unsigned)h) << 16; return v.f;
}
__device__ __forceinline__ void unpack2(unsigned u, float& lo, float& hi) {
    union { unsigned u; float f; } a, b;
    a.u = u << 16; b.u = u & 0xffff0000u;
    lo = a.f; hi = b.f;
}
__device__ __forceinline__ void load_lds16(const void* g, void* l) {
    __builtin_amdgcn_global_load_lds(
        (const __attribute__((address_space(1))) unsigned int*)g,
        (__attribute__((address_space(3))) unsigned int*)l, 16, 0, 0);
}

// ---------------- fp32 -> bf16 (vector) ----------------
__global__ void k_f2b4(const float* __restrict__ in, u16* __restrict__ out, int n4) {
    int i = blockIdx.x * 256 + threadIdx.x;
    if (i < n4) {
        float4 v = ((const float4*)in)[i];
        unsigned lo = (unsigned)f2bf(v.x) | ((unsigned)f2bf(v.y) << 16);
        unsigned hi = (unsigned)f2bf(v.z) | ((unsigned)f2bf(v.w) << 16);
        ((uint2*)out)[i] = make_uint2(lo, hi);
    }
}

// ---------------- transpose fp32[K][N] -> bf16[Npad][K] ----------------
__global__ void k_transpose_f2b(const float* __restrict__ W, u16* __restrict__ Wt,
                                int K, int N) {
    __shared__ float tile[32][33];
    int nt = blockIdx.x * 32, kt = blockIdx.y * 32;
    int tx = threadIdx.x, ty = threadIdx.y;
    #pragma unroll
    for (int r = 0; r < 32; r += 8) {
        int k = kt + ty + r, n = nt + tx;
        tile[ty + r][tx] = (n < N && k < K) ? W[(size_t)k * N + n] : 0.f;
    }
    __syncthreads();
    #pragma unroll
    for (int r = 0; r < 32; r += 8) {
        int n = nt + ty + r, k = kt + tx;
        Wt[(size_t)n * K + k] = f2bf(tile[tx][ty + r]);
    }
}

// ---------------- 128x128 bf16 MFMA GEMM, LDS double-buffered (r9-frozen) ----------------
template <int EPI>
__global__ __launch_bounds__(256) void gemm_bt(
    const u16* __restrict__ A, const u16* __restrict__ Bt, int M, int N, int K,
    float* __restrict__ outF,
    u16* __restrict__ zb, u16* __restrict__ xbc, float* __restrict__ dtq,
    const float* __restrict__ dt_bias) {
    __shared__ u16 As[2 * 8192];   // 2 x 128x64 bf16
    __shared__ u16 Bs[2 * 8192];
    int t = threadIdx.x;
    int w = t >> 6, lane = t & 63;
    int m0 = blockIdx.y * 128, n0 = blockIdx.x * 128;
    int wm = (w >> 1) * 64, wn = (w & 1) * 64;
    floatx4 acc[4][4];
    #pragma unroll
    for (int i = 0; i < 4; i++)
        #pragma unroll
        for (int j = 0; j < 4; j++) acc[i][j] = (floatx4){0.f, 0.f, 0.f, 0.f};

    const int nt = K >> 6;
    const int byte0 = (w * 4) * 1024 + lane * 16;

    auto stage = [&](int sel, int k0) {
        #pragma unroll
        for (int i = 0; i < 4; i++) {
            int byte = byte0 + i * 1024;
            int row = byte >> 7;
            int colb = (byte & 127) ^ ((row & 7) << 4);
            load_lds16(A + (size_t)(m0 + row) * K + k0 + (colb >> 1),
                       (char*)As + sel * 16384 + byte);
            load_lds16(Bt + (size_t)(n0 + row) * K + k0 + (colb >> 1),
                       (char*)Bs + sel * 16384 + byte);
        }
    };

    stage(0, 0);
    __syncthreads();
    int cur = 0;
    for (int kt = 0; kt < nt; ++kt) {
        if (kt + 1 < nt) stage(cur ^ 1, (kt + 1) << 6);
        const u16* Ab = As + cur * 8192;
        const u16* Bb = Bs + cur * 8192;
        #pragma unroll
        for (int ks = 0; ks < 2; ks++) {
            int kk = ks * 32 + ((lane >> 4) << 3);
            bhalf8 af[4], bf[4];
            #pragma unroll
            for (int mi = 0; mi < 4; mi++) {
                int row = wm + mi * 16 + (lane & 15);
                int idx = (row * 64 + kk) ^ ((row & 7) << 3);
                af[mi] = *(const bhalf8*)(Ab + idx);
            }
            #pragma unroll
            for (int ni = 0; ni < 4; ni++) {
                int col = wn + ni * 16 + (lane & 15);
                int idx = (col * 64 + kk) ^ ((col & 7) << 3);
                bf[ni] = *(const bhalf8*)(Bb + idx);
            }
            #pragma unroll
            for (int mi = 0; mi < 4; mi++)
                #pragma unroll
                for (int ni = 0; ni < 4; ni++)
                    acc[mi][ni] = __builtin_amdgcn_mfma_f32_16x16x32_bf16(
                        af[mi], bf[ni], acc[mi][ni], 0, 0, 0);
        }
        __syncthreads();
        cur ^= 1;
    }
    #pragma unroll
    for (int mi = 0; mi < 4; mi++) {
        #pragma unroll
        for (int ni = 0; ni < 4; ni++) {
            floatx4 v = acc[mi][ni];
            int col = n0 + wn + ni * 16 + (lane & 15);
            #pragma unroll
            for (int r = 0; r < 4; r++) {
                int row = m0 + wm + mi * 16 + ((lane >> 4) << 2) + r;
                float val = v[r];
                if (EPI == 0) {
                    outF[(size_t)row * N + col] = val;
                } else {
                    if (col < 4096) {
                        zb[(size_t)row * 4096 + col] = f2bf(val);
                    } else if (col < 8448) {
                        xbc[(size_t)row * 4352 + (col - 4096)] = f2bf(val);
                    } else if (col < 8512) {
                        int h = col - 8448;
                        float xv = val + dt_bias[h];
                        float sp = (xv > 20.f) ? xv : log1pf(__expf(xv));
                        dtq[(size_t)row * 64 + h] = sp;
                    }
                }
            }
        }
    }
}

// ---------------- causal depthwise conv(4) + silu + split (8-row tiles) ----------------
__global__ __launch_bounds__(256) void k_conv(
    const u16* __restrict__ xbc, const float* __restrict__ conv_w,
    const float* __restrict__ conv_b,
    u16* __restrict__ x, u16* __restrict__ Bo, u16* __restrict__ Co) {
    int bid = blockIdx.x;            // 512 = 2 b * 256 l-tiles
    int b = bid >> 8, lt = bid & 255;
    int l0 = lt * 8;
    size_t rb = (size_t)(b * 2048) * 4352;
    for (int ch = threadIdx.x; ch < 4352; ch += 256) {
        float w0 = conv_w[ch * 4 + 0], w1 = conv_w[ch * 4 + 1];
        float w2 = conv_w[ch * 4 + 2], w3 = conv_w[ch * 4 + 3];
        float bc = conv_b[ch];
        float h0 = (l0 >= 3) ? b2f(xbc[rb + (size_t)(l0 - 3) * 4352 + ch]) : 0.f;
        float h1 = (l0 >= 2) ? b2f(xbc[rb + (size_t)(l0 - 2) * 4352 + ch]) : 0.f;
        float h2 = (l0 >= 1) ? b2f(xbc[rb + (size_t)(l0 - 1) * 4352 + ch]) : 0.f;
        #pragma unroll
        for (int i = 0; i < 8; i++) {
            int l = l0 + i;
            float xc = b2f(xbc[rb + (size_t)l * 4352 + ch]);
            float acc = bc + w0 * h0 + w1 * h1 + w2 * h2 + w3 * xc;
            float v = acc / (1.f + __expf(-acc));   // silu
            int row = b * 2048 + l;
            if (ch < 4096) {
                x[(size_t)row * 4096 + ch] = f2bf(v);
            } else if (ch < 4224) {
                Bo[(size_t)row * 128 + (ch - 4096)] = f2bf(v);
            } else {
                Co[(size_t)row * 128 + (ch - 4224)] = f2bf(v);
            }
            h0 = h1; h1 = h2; h2 = xc;
        }
    }
}

// ---------------- per-chunk cumsum of A*dt + chunk totals ----------------
__global__ void k_dtprep(const float* __restrict__ dtq, const float* __restrict__ A_log,
                         float* __restrict__ acum, float* __restrict__ Tc) {
    int bc = blockIdx.x;     // b*32 + c
    int h = threadIdx.x;     // 64 threads
    float A = -__expf(A_log[h]);
    float s = 0.f;
    #pragma unroll
    for (int l = 0; l < 64; l++) {
        int row = bc * 64 + l;
        s += A * dtq[row * 64 + h];
        acum[(size_t)row * 64 + h] = s;
    }
    int b = bc >> 5, c = bc & 31;
    Tc[(b * 64 + h) * 32 + c] = s;
}

// ---------------- G = C * B^T per (b,c); 256 blocks (16 l-rows each) ----------------
__global__ __launch_bounds__(256) void k_G(const u16* __restrict__ Bo, const u16* __restrict__ Co,
                                           float* __restrict__ G) {
    int bc = blockIdx.x;
    int lq = blockIdx.y;             // 0..3, 16 l-rows per block
    __shared__ float BsT[128][68];   // [n][s]
    __shared__ float Cs[16][132];    // [l][n]
    int t = threadIdx.x;
    for (int idx = t; idx < 64 * 128; idx += 256) {
        int r = idx >> 7, n = idx & 127;
        BsT[n][r] = b2f(Bo[(size_t)(bc * 64 + r) * 128 + n]);
    }
    for (int idx = t; idx < 16 * 128; idx += 256) {
        int r = idx >> 7, n = idx & 127;
        Cs[r][n] = b2f(Co[(size_t)(bc * 64 + lq * 16 + r) * 128 + n]);
    }
    __syncthreads();
    int lr = t >> 4, sq = t & 15;    // l-row 0..15, s-quad 0..15 (4 s each)
    int l = lq * 16 + lr;
    float a[4] = {0.f, 0.f, 0.f, 0.f};
    for (int n = 0; n < 128; n++) {
        float cv = Cs[lr][n];
        const float4* bp = (const float4*)&BsT[n][sq * 4];
        float4 b0 = bp[0];
        a[0] += cv * b0.x; a[1] += cv * b0.y; a[2] += cv * b0.z; a[3] += cv * b0.w;
    }
    size_t gb = ((size_t)bc * 64 + l) * 64 + sq * 4;
    #pragma unroll
    for (int i = 0; i < 4; i++) G[gb + i] = a[i];
}

// ---------------- Y_diag + chunk states per (b,c,h), MFMA ----------------
__global__ __launch_bounds__(256) void k_diag(
    const u16* __restrict__ xb, const u16* __restrict__ Bo,
    const float* __restrict__ G, const float* __restrict__ acum,
    const float* __restrict__ dtq,
    u16* __restrict__ y, u16* __restrict__ cs) {
    int bc = blockIdx.x, h = blockIdx.y;
    __shared__ u16 XT[4096];    // [p][s] = x[s][p]*dt[s]
    __shared__ u16 Pl[4096];    // [l][s]
    __shared__ u16 BTd[8192];   // [n][l] = B[l][n]*dec[l]
    __shared__ float ac[64], dec[64], dts[64];
    int t = threadIdx.x, w = t >> 6, lane = t & 63;
    if (t < 64) {
        ac[t] = acum[(size_t)(bc * 64 + t) * 64 + h];
        dts[t] = dtq[(size_t)(bc * 64 + t) * 64 + h];
    }
    __syncthreads();
    if (t < 64) dec[t] = __expf(ac[63] - ac[t]);
    for (int idx = t; idx < 4096; idx += 256) {
        int s = idx >> 6, p = idx & 63;
        float v = b2f(xb[(size_t)(bc * 64 + s) * 4096 + h * 64 + p]) * dts[s];
        XT[(p << 6) + (s ^ ((p & 7) << 3))] = f2bf(v);
    }
    for (int idx = t; idx < 4096; idx += 256) {
        int l = idx >> 6, s = idx & 63;
        float v = (s <= l) ? __expf(ac[l] - ac[s]) * G[((size_t)bc * 64 + l) * 64 + s] : 0.f;
        Pl[(l << 6) + (s ^ ((l & 7) << 3))] = f2bf(v);
    }
    __syncthreads();                     // dec ready
    for (int idx = t; idx < 8192; idx += 256) {
        int l = idx >> 7, n = idx & 127;
        float v = b2f(Bo[(size_t)(bc * 64 + l) * 128 + n]) * dec[l];
        BTd[(n << 6) + (l ^ ((n & 7) << 3))] = f2bf(v);
    }
    __syncthreads();
    // ---- Y_diag: wave w owns l-rows [16w,16w+16); 4 p-tiles; K=64
    {
        floatx4 accY[4];
        #pragma unroll
        for (int ni = 0; ni < 4; ni++) accY[ni] = (floatx4){0.f, 0.f, 0.f, 0.f};
        int row = (w << 4) + (lane & 15);
        #pragma unroll
        for (int ks = 0; ks < 2; ks++) {
            int k = (ks << 5) + ((lane >> 4) << 3);
            int kx = k ^ ((row & 7) << 3);
            bhalf8 af = *(const bhalf8*)(Pl + (row << 6) + kx);
            #pragma unroll
            for (int ni = 0; ni < 4; ni++) {
                int pr = (ni << 4) + (lane & 15);
                bhalf8 bf = *(const bhalf8*)(XT + (pr << 6) + kx);
                accY[ni] = __builtin_amdgcn_mfma_f32_16x16x32_bf16(af, bf, accY[ni], 0, 0, 0);
            }
        }
        #pragma unroll
        for (int ni = 0; ni < 4; ni++) {
            int col = (ni << 4) + (lane & 15);
            #pragma unroll
            for (int r = 0; r < 4; r++) {
                int l = (w << 4) + ((lane >> 4) << 2) + r;
                y[(size_t)(bc * 64 + l) * 4096 + h * 64 + col] = f2bf(accY[ni][r]);
            }
        }
    }
    // ---- chunk state: wave w owns p-rows [16w,16w+16); 8 n-tiles; K=64
    {
        floatx4 accS[8];
        #pragma unroll
        for (int ni = 0; ni < 8; ni++) accS[ni] = (floatx4){0.f, 0.f, 0.f, 0.f};
        int prow = (w << 4) + (lane & 15);
        #pragma unroll
        for (int ks = 0; ks < 2; ks++) {
            int k = (ks << 5) + ((lane >> 4) << 3);
            int kx = k ^ ((prow & 7) << 3);
            bhalf8 af = *(const bhalf8*)(XT + (prow << 6) + kx);
            #pragma unroll
            for (int ni = 0; ni < 8; ni++) {
                int nr = (ni << 4) + (lane & 15);
                bhalf8 bf = *(const bhalf8*)(BTd + (nr << 6) + kx);
                accS[ni] = __builtin_amdgcn_mfma_f32_16x16x32_bf16(af, bf, accS[ni], 0, 0, 0);
            }
        }
        #pragma unroll
        for (int ni = 0; ni < 8; ni++) {
            int n = (ni << 4) + (lane & 15);
            #pragma unroll
            for (int r = 0; r < 4; r++) {
                int p = (w << 4) + ((lane >> 4) << 2) + r;
                cs[((size_t)(bc * 64 + h) * 64 + p) * 128 + n] = f2bf(accS[ni][r]);
            }
        }
    }
}

// ---------------- fused chunk-prefix scan + Y_off per (b,h) ----------------
// Keeps running prefix P[p][n] in LDS: fp32 master + bf16 mirror (swizzled,
// MFMA B-operand).  Per chunk c: stage C_c/S_c -> (c>0) yoff MFMA from
// P-mirror -> update P32 = exp(Tc)*P32 + S_c, refresh mirror.  Eliminates the
// separate scan RMW pass (134 MB) and one launch.  Each block exclusively
// owns its (b,h) y-columns and P state; 3 __syncthreads per c.
__global__ __launch_bounds__(512) void k_scanyoff(
    const u16* __restrict__ Co, const u16* __restrict__ cs,
    const float* __restrict__ acum, const float* __restrict__ Tc,
    u16* __restrict__ y) {
    int bh = blockIdx.x;            // 0..127 = b*64 + h
    int b = bh >> 6, h = bh & 63;
    __shared__ u16 Cl[8192];        // C chunk [l][n], swz ^((l&15)<<3)
    __shared__ u16 Pbf[8192];       // P mirror [p][n], swz ^((p&15)<<3)
    __shared__ u16 Sc[8192];        // S_c raw [p][n]
    __shared__ float P32[8192];     // prefix fp32 [p][n]
    __shared__ float od[64];
    int t = threadIdx.x, w = t >> 6, lane = t & 63;
    for (int i = t; i < 8192; i += 512) P32[i] = 0.f;
    const float* Tp = Tc + bh * 32;
    const int lt = w >> 1, ph = w & 1;     // wave -> (l-tile 0..3, p-half 0..1)
    int lrow = (lt << 4) + (lane & 15);
    for (int c = 0; c < 32; ++c) {
        int bc = b * 32 + c;
        for (int idx = t; idx < 8192; idx += 512) {
            int l = idx >> 7, n = idx & 127;
            Cl[(l << 7) + (n ^ ((l & 15) << 3))] = Co[(size_t)(bc * 64 + l) * 128 + n];
            Sc[idx] = cs[(size_t)(bc * 64 + h) * 8192 + idx];
        }
        if (t < 64) od[t] = __expf(acum[(size_t)(bc * 64 + t) * 64 + h]);
        __syncthreads();
        if (c > 0) {
            floatx4 acc[2];
            acc[0] = (floatx4){0.f, 0.f, 0.f, 0.f};
            acc[1] = (floatx4){0.f, 0.f, 0.f, 0.f};
            #pragma unroll
            for (int ks = 0; ks < 4; ks++) {
                int k = (ks << 5) + ((lane >> 4) << 3);
                int kx = k ^ ((lrow & 15) << 3);      // lrow&15 == pr&15
                bhalf8 af = *(const bhalf8*)(Cl + (lrow << 7) + kx);
                #pragma unroll
                for (int j = 0; j < 2; j++) {
                    int pr = ((ph * 2 + j) << 4) + (lane & 15);
                    bhalf8 bf = *(const bhalf8*)(Pbf + (pr << 7) + kx);
                    acc[j] = __builtin_amdgcn_mfma_f32_16x16x32_bf16(af, bf, acc[j], 0, 0, 0);
                }
            }
            #pragma unroll
            for (int j = 0; j < 2; j++) {
                int col = ((ph * 2 + j) << 4) + (lane & 15);
                #pragma unroll
                for (int r = 0; r < 4; r++) {
                    int l = (lt << 4) + ((lane >> 4) << 2) + r;
                    size_t yi = (size_t)(bc * 64 + l) * 4096 + h * 64 + col;
                    y[yi] = f2bf(b2f(y[yi]) + od[l] * acc[j][r]);
                }
            }
        }
        __syncthreads();                  // MFMA reads of Pbf done
        float eT = __expf(Tp[c]);
        for (int idx = t; idx < 8192; idx += 512) {
            float pv = eT * P32[idx] + b2f(Sc[idx]);
            P32[idx] = pv;
            int p = idx >> 7, n = idx & 127;
            Pbf[(p << 7) + (n ^ ((p & 15) << 3))] = f2bf(pv);
        }
        __syncthreads();                  // P ready for next c
    }
}

// ---------------- gating (silu(z)) + D skip + RMSNorm -> bf16 ----------------
__global__ __launch_bounds__(256) void k_norm(
    const u16* __restrict__ y, const u16* __restrict__ x, const u16* __restrict__ z,
    const float* __restrict__ D_param, const float* __restrict__ norm_w,
    u16* __restrict__ ynorm) {
    int row = blockIdx.x;
    int t = threadIdx.x;
    size_t base = (size_t)row * 4096 + (size_t)t * 16;
    float yv[16], xf[16], zf[16];
    {
        uint4 a = ((const uint4*)(y + base))[0];
        uint4 b = ((const uint4*)(y + base))[1];
        unpack2(a.x, yv[0], yv[1]); unpack2(a.y, yv[2], yv[3]);
        unpack2(a.z, yv[4], yv[5]); unpack2(a.w, yv[6], yv[7]);
        unpack2(b.x, yv[8], yv[9]); unpack2(b.y, yv[10], yv[11]);
        unpack2(b.z, yv[12], yv[13]); unpack2(b.w, yv[14], yv[15]);
    }
    {
        uint4 a = ((const uint4*)(x + base))[0];
        uint4 b = ((const uint4*)(x + base))[1];
        unpack2(a.x, xf[0], xf[1]); unpack2(a.y, xf[2], xf[3]);
        unpack2(a.z, xf[4], xf[5]); unpack2(a.w, xf[6], xf[7]);
        unpack2(b.x, xf[8], xf[9]); unpack2(b.y, xf[10], xf[11]);
        unpack2(b.z, xf[12], xf[13]); unpack2(b.w, xf[14], xf[15]);
    }
    {
        uint4 a = ((const uint4*)(z + base))[0];
        uint4 b = ((const uint4*)(z + base))[1];
        unpack2(a.x, zf[0], zf[1]); unpack2(a.y, zf[2], zf[3]);
        unpack2(a.z, zf[4], zf[5]); unpack2(a.w, zf[6], zf[7]);
        unpack2(b.x, zf[8], zf[9]); unpack2(b.y, zf[10], zf[11]);
        unpack2(b.z, zf[12], zf[13]); unpack2(b.w, zf[14], zf[15]);
    }
    float D = D_param[t >> 2];
    float vals[16], ss = 0.f;
    #pragma unroll
    for (int j = 0; j < 16; j++) {
        float v = yv[j] + xf[j] * D;
        float zz = zf[j];
        float yf = v * (zz / (1.f + __expf(-zz)));
        vals[j] = yf;
        ss += yf * yf;
    }
    #pragma unroll
    for (int o = 32; o > 0; o >>= 1) ss += __shfl_down(ss, o, 64);
    __shared__ float red[4];
    if ((t & 63) == 0) red[t >> 6] = ss;
    __syncthreads();
    float tot = red[0] + red[1] + red[2] + red[3];
    float rr = rsqrtf(tot * (1.f / 4096.f) + 1e-5f);
    unsigned o32[8];
    #pragma unroll
    for (int j = 0; j < 8; j++) {
        float lo = vals[2 * j] * rr * norm_w[t * 16 + 2 * j];
        float hi = vals[2 * j + 1] * rr * norm_w[t * 16 + 2 * j + 1];
        o32[j] = (unsigned)f2bf(lo) | ((unsigned)f2bf(hi) << 16);
    }
    uint4 w0, w1;
    w0.x = o32[0]; w0.y = o32[1]; w0.z = o32[2]; w0.w = o32[3];
    w1.x = o32[4]; w1.y = o32[5]; w1.z = o32[6]; w1.w = o32[7];
    ((uint4*)(ynorm + base))[0] = w0;
    ((uint4*)(ynorm + base))[1] = w1;
}

// ---------------- launch ----------------
extern "C" void kernel_launch(void* const* d_in, const int* in_sizes, int n_in,
                              void* d_out, int out_size, void* d_ws, size_t ws_size,
                              hipStream_t stream) {
    const float* u       = (const float*)d_in[0];
    const float* W_in    = (const float*)d_in[1];
    const float* conv_w  = (const float*)d_in[2];
    const float* conv_b  = (const float*)d_in[3];
    const float* dt_bias = (const float*)d_in[4];
    const float* A_log   = (const float*)d_in[5];
    const float* D_param = (const float*)d_in[6];
    const float* norm_w  = (const float*)d_in[7];
    const float* W_out   = (const float*)d_in[8];
    float* out = (float*)d_out;

    // ---- workspace budget (lifetime-aliased) ----
    const size_t REGION = (size_t)134217728;
    size_t need = REGION
                + (size_t)33554432   // zb
                + (size_t)33554432   // xb
                + (size_t)1048576    // Bo
                + (size_t)1048576    // Co
                + (size_t)1048576    // acum
                + (size_t)16384      // Tc
                + (size_t)1048576    // G
                + (size_t)1048576    // dtq
                + (size_t)33554432;  // yb
    if (ws_size < need) return;      // diagnostic: clean absmax fail, no fault

    char* ws = (char*)d_ws;
    // transient region overlays
    u16*   ubf   = (u16*)(ws);
    u16*   WinT  = (u16*)(ws + 16777216);
    u16*   xbc   = (u16*)(ws + 16777216 + 35651584);
    u16*   cs    = (u16*)(ws);
    u16*   WoutT = (u16*)(ws);
    u16*   ynorm = (u16*)(ws + 16777216);
    // persistent
    char* p = ws + REGION;
    u16*   zb    = (u16*)p;            p += 33554432;
    u16*   xb    = (u16*)p;            p += 33554432;
    u16*   Bo    = (u16*)p;            p += 1048576;
    u16*   Co    = (u16*)p;            p += 1048576;
    float* acum  = (float*)p;          p += 1048576;
    float* Tc    = (float*)p;          p += 16384;
    float* G     = (float*)p;          p += 1048576;
    float* dtq   = (float*)p;          p += 1048576;
    u16*   yb    = (u16*)p;            p += 33554432;

    // 1. u -> bf16
    k_f2b4<<<8192, 256, 0, stream>>>(u, ubf, 4096 * 2048 / 4);
    // 2. W_in -> bf16 transposed, padded to 8576 rows (67 x 128-tiles)
    k_transpose_f2b<<<dim3(268, 64), dim3(32, 8), 0, stream>>>(W_in, WinT, 2048, 8512);
    // 3. in_proj GEMM (LDS dbuf) + split/softplus epilogue; plain 2D grid
    gemm_bt<1><<<dim3(67, 32), 256, 0, stream>>>(ubf, WinT, 4096, 8576, 2048,
                                                 nullptr, zb, xbc, dtq, dt_bias);
    // 4. conv + silu + split (x, B, C); 8-row register-ring tiles
    k_conv<<<512, 256, 0, stream>>>(xbc, conv_w, conv_b, xb, Bo, Co);
    // 5. cumsum(A*dt) per chunk + chunk totals
    k_dtprep<<<64, 64, 0, stream>>>(dtq, A_log, acum, Tc);
    // 6. G = C B^T (256 blocks)
    k_G<<<dim3(64, 4), 256, 0, stream>>>(Bo, Co, G);
    // 7. Y_diag + chunk states, MFMA  (xbc dead -> cs overlays region)
    k_diag<<<dim3(64, 64), 256, 0, stream>>>(xb, Bo, G, acum, dtq, yb, cs);
    // 8. fused chunk-prefix scan + Y_off (replaces k_scan + k_yoff)
    k_scanyoff<<<128, 512, 0, stream>>>(Co, cs, acum, Tc, yb);
    // 9. W_out -> bf16 transposed (cs dead -> WoutT overlays region)
    k_transpose_f2b<<<dim3(64, 128), dim3(32, 8), 0, stream>>>(W_out, WoutT, 4096, 2048);
    // 10. gating + D skip + RMSNorm -> bf16
    k_norm<<<4096, 256, 0, stream>>>(yb, xb, zb, D_param, norm_w, ynorm);
    // 11. out_proj GEMM (LDS dbuf) -> fp32 out; plain 2D grid
    gemm_bt<0><<<dim3(16, 32), 256, 0, stream>>>(ynorm, WoutT, 4096, 2048, 4096,
                                                 out, nullptr, nullptr, nullptr, nullptr);
    (void)in_sizes; (void)n_in; (void)out_size;
}

// Round 11
// 607.530 us; speedup vs baseline: 1.1080x; 1.1080x over previous
//
#include <hip/hip_runtime.h>

typedef unsigned short u16;
typedef __attribute__((ext_vector_type(8))) short bhalf8;   // 8 bf16 in 4 VGPRs
typedef __attribute__((ext_vector_type(4))) float floatx4;

// ---------------- helpers ----------------
__device__ __forceinline__ u16 f2bf(float f) {
    union { float f; unsigned u; } v; v.f = f;
    unsigned u = v.u;
    unsigned r = u + 0x7fffu + ((u >> 16) & 1u);
    return (u16)(r >> 16);
}
__device__ __forceinline__ float b2f(u16 h) {
    union { unsigned u; float f; } v; v.u = ((unsigned)h) << 16; return v.f;
}
__device__ __forceinline__ void unpack2(unsigned u, float& lo, float& hi) {
    union { unsigned u; float f; } a, b;
    a.u = u << 16; b.u = u & 0xffff0000u;
    lo = a.f; hi = b.f;
}
__device__ __forceinline__ void load_lds16(const void* g, void* l) {
    __builtin_amdgcn_global_load_lds(
        (const __attribute__((address_space(1))) unsigned int*)g,
        (__attribute__((address_space(3))) unsigned int*)l, 16, 0, 0);
}

// ---------------- fp32 -> bf16 (vector) ----------------
__global__ void k_f2b4(const float* __restrict__ in, u16* __restrict__ out, int n4) {
    int i = blockIdx.x * 256 + threadIdx.x;
    if (i < n4) {
        float4 v = ((const float4*)in)[i];
        unsigned lo = (unsigned)f2bf(v.x) | ((unsigned)f2bf(v.y) << 16);
        unsigned hi = (unsigned)f2bf(v.z) | ((unsigned)f2bf(v.w) << 16);
        ((uint2*)out)[i] = make_uint2(lo, hi);
    }
}

// ---------------- transpose fp32[K][N] -> bf16[Npad][K] ----------------
__global__ void k_transpose_f2b(const float* __restrict__ W, u16* __restrict__ Wt,
                                int K, int N) {
    __shared__ float tile[32][33];
    int nt = blockIdx.x * 32, kt = blockIdx.y * 32;
    int tx = threadIdx.x, ty = threadIdx.y;
    #pragma unroll
    for (int r = 0; r < 32; r += 8) {
        int k = kt + ty + r, n = nt + tx;
        tile[ty + r][tx] = (n < N && k < K) ? W[(size_t)k * N + n] : 0.f;
    }
    __syncthreads();
    #pragma unroll
    for (int r = 0; r < 32; r += 8) {
        int n = nt + ty + r, k = kt + tx;
        Wt[(size_t)n * K + k] = f2bf(tile[tx][ty + r]);
    }
}

// ---------------- 128x128 bf16 MFMA GEMM, LDS double-buffered (r9-frozen) ----------------
template <int EPI>
__global__ __launch_bounds__(256) void gemm_bt(
    const u16* __restrict__ A, const u16* __restrict__ Bt, int M, int N, int K,
    float* __restrict__ outF,
    u16* __restrict__ zb, u16* __restrict__ xbc, float* __restrict__ dtq,
    const float* __restrict__ dt_bias) {
    __shared__ u16 As[2 * 8192];   // 2 x 128x64 bf16
    __shared__ u16 Bs[2 * 8192];
    int t = threadIdx.x;
    int w = t >> 6, lane = t & 63;
    int m0 = blockIdx.y * 128, n0 = blockIdx.x * 128;
    int wm = (w >> 1) * 64, wn = (w & 1) * 64;
    floatx4 acc[4][4];
    #pragma unroll
    for (int i = 0; i < 4; i++)
        #pragma unroll
        for (int j = 0; j < 4; j++) acc[i][j] = (floatx4){0.f, 0.f, 0.f, 0.f};

    const int nt = K >> 6;
    const int byte0 = (w * 4) * 1024 + lane * 16;

    auto stage = [&](int sel, int k0) {
        #pragma unroll
        for (int i = 0; i < 4; i++) {
            int byte = byte0 + i * 1024;
            int row = byte >> 7;
            int colb = (byte & 127) ^ ((row & 7) << 4);
            load_lds16(A + (size_t)(m0 + row) * K + k0 + (colb >> 1),
                       (char*)As + sel * 16384 + byte);
            load_lds16(Bt + (size_t)(n0 + row) * K + k0 + (colb >> 1),
                       (char*)Bs + sel * 16384 + byte);
        }
    };

    stage(0, 0);
    __syncthreads();
    int cur = 0;
    for (int kt = 0; kt < nt; ++kt) {
        if (kt + 1 < nt) stage(cur ^ 1, (kt + 1) << 6);
        const u16* Ab = As + cur * 8192;
        const u16* Bb = Bs + cur * 8192;
        #pragma unroll
        for (int ks = 0; ks < 2; ks++) {
            int kk = ks * 32 + ((lane >> 4) << 3);
            bhalf8 af[4], bf[4];
            #pragma unroll
            for (int mi = 0; mi < 4; mi++) {
                int row = wm + mi * 16 + (lane & 15);
                int idx = (row * 64 + kk) ^ ((row & 7) << 3);
                af[mi] = *(const bhalf8*)(Ab + idx);
            }
            #pragma unroll
            for (int ni = 0; ni < 4; ni++) {
                int col = wn + ni * 16 + (lane & 15);
                int idx = (col * 64 + kk) ^ ((col & 7) << 3);
                bf[ni] = *(const bhalf8*)(Bb + idx);
            }
            #pragma unroll
            for (int mi = 0; mi < 4; mi++)
                #pragma unroll
                for (int ni = 0; ni < 4; ni++)
                    acc[mi][ni] = __builtin_amdgcn_mfma_f32_16x16x32_bf16(
                        af[mi], bf[ni], acc[mi][ni], 0, 0, 0);
        }
        __syncthreads();
        cur ^= 1;
    }
    #pragma unroll
    for (int mi = 0; mi < 4; mi++) {
        #pragma unroll
        for (int ni = 0; ni < 4; ni++) {
            floatx4 v = acc[mi][ni];
            int col = n0 + wn + ni * 16 + (lane & 15);
            #pragma unroll
            for (int r = 0; r < 4; r++) {
                int row = m0 + wm + mi * 16 + ((lane >> 4) << 2) + r;
                float val = v[r];
                if (EPI == 0) {
                    outF[(size_t)row * N + col] = val;
                } else {
                    if (col < 4096) {
                        zb[(size_t)row * 4096 + col] = f2bf(val);
                    } else if (col < 8448) {
                        xbc[(size_t)row * 4352 + (col - 4096)] = f2bf(val);
                    } else if (col < 8512) {
                        int h = col - 8448;
                        float xv = val + dt_bias[h];
                        float sp = (xv > 20.f) ? xv : log1pf(__expf(xv));
                        dtq[(size_t)row * 64 + h] = sp;
                    }
                }
            }
        }
    }
}

// ---------------- causal depthwise conv(4) + silu + split (8-row tiles) ----------------
__global__ __launch_bounds__(256) void k_conv(
    const u16* __restrict__ xbc, const float* __restrict__ conv_w,
    const float* __restrict__ conv_b,
    u16* __restrict__ x, u16* __restrict__ Bo, u16* __restrict__ Co) {
    int bid = blockIdx.x;            // 512 = 2 b * 256 l-tiles
    int b = bid >> 8, lt = bid & 255;
    int l0 = lt * 8;
    size_t rb = (size_t)(b * 2048) * 4352;
    for (int ch = threadIdx.x; ch < 4352; ch += 256) {
        float w0 = conv_w[ch * 4 + 0], w1 = conv_w[ch * 4 + 1];
        float w2 = conv_w[ch * 4 + 2], w3 = conv_w[ch * 4 + 3];
        float bc = conv_b[ch];
        float h0 = (l0 >= 3) ? b2f(xbc[rb + (size_t)(l0 - 3) * 4352 + ch]) : 0.f;
        float h1 = (l0 >= 2) ? b2f(xbc[rb + (size_t)(l0 - 2) * 4352 + ch]) : 0.f;
        float h2 = (l0 >= 1) ? b2f(xbc[rb + (size_t)(l0 - 1) * 4352 + ch]) : 0.f;
        #pragma unroll
        for (int i = 0; i < 8; i++) {
            int l = l0 + i;
            float xc = b2f(xbc[rb + (size_t)l * 4352 + ch]);
            float acc = bc + w0 * h0 + w1 * h1 + w2 * h2 + w3 * xc;
            float v = acc / (1.f + __expf(-acc));   // silu
            int row = b * 2048 + l;
            if (ch < 4096) {
                x[(size_t)row * 4096 + ch] = f2bf(v);
            } else if (ch < 4224) {
                Bo[(size_t)row * 128 + (ch - 4096)] = f2bf(v);
            } else {
                Co[(size_t)row * 128 + (ch - 4224)] = f2bf(v);
            }
            h0 = h1; h1 = h2; h2 = xc;
        }
    }
}

// ---------------- per-chunk cumsum of A*dt + chunk totals ----------------
__global__ void k_dtprep(const float* __restrict__ dtq, const float* __restrict__ A_log,
                         float* __restrict__ acum, float* __restrict__ Tc) {
    int bc = blockIdx.x;     // b*32 + c
    int h = threadIdx.x;     // 64 threads
    float A = -__expf(A_log[h]);
    float s = 0.f;
    #pragma unroll
    for (int l = 0; l < 64; l++) {
        int row = bc * 64 + l;
        s += A * dtq[row * 64 + h];
        acum[(size_t)row * 64 + h] = s;
    }
    int b = bc >> 5, c = bc & 31;
    Tc[(b * 64 + h) * 32 + c] = s;
}

// ---------------- G = C * B^T per (b,c); 256 blocks (16 l-rows each) ----------------
__global__ __launch_bounds__(256) void k_G(const u16* __restrict__ Bo, const u16* __restrict__ Co,
                                           float* __restrict__ G) {
    int bc = blockIdx.x;
    int lq = blockIdx.y;             // 0..3, 16 l-rows per block
    __shared__ float BsT[128][68];   // [n][s]
    __shared__ float Cs[16][132];    // [l][n]
    int t = threadIdx.x;
    for (int idx = t; idx < 64 * 128; idx += 256) {
        int r = idx >> 7, n = idx & 127;
        BsT[n][r] = b2f(Bo[(size_t)(bc * 64 + r) * 128 + n]);
    }
    for (int idx = t; idx < 16 * 128; idx += 256) {
        int r = idx >> 7, n = idx & 127;
        Cs[r][n] = b2f(Co[(size_t)(bc * 64 + lq * 16 + r) * 128 + n]);
    }
    __syncthreads();
    int lr = t >> 4, sq = t & 15;    // l-row 0..15, s-quad 0..15 (4 s each)
    int l = lq * 16 + lr;
    float a[4] = {0.f, 0.f, 0.f, 0.f};
    for (int n = 0; n < 128; n++) {
        float cv = Cs[lr][n];
        const float4* bp = (const float4*)&BsT[n][sq * 4];
        float4 b0 = bp[0];
        a[0] += cv * b0.x; a[1] += cv * b0.y; a[2] += cv * b0.z; a[3] += cv * b0.w;
    }
    size_t gb = ((size_t)bc * 64 + l) * 64 + sq * 4;
    #pragma unroll
    for (int i = 0; i < 4; i++) G[gb + i] = a[i];
}

// ---------------- Y_diag + chunk states per (b,c,h), MFMA ----------------
__global__ __launch_bounds__(256) void k_diag(
    const u16* __restrict__ xb, const u16* __restrict__ Bo,
    const float* __restrict__ G, const float* __restrict__ acum,
    const float* __restrict__ dtq,
    u16* __restrict__ y, u16* __restrict__ cs) {
    int bc = blockIdx.x, h = blockIdx.y;
    __shared__ u16 XT[4096];    // [p][s] = x[s][p]*dt[s]
    __shared__ u16 Pl[4096];    // [l][s]
    __shared__ u16 BTd[8192];   // [n][l] = B[l][n]*dec[l]
    __shared__ float ac[64], dec[64], dts[64];
    int t = threadIdx.x, w = t >> 6, lane = t & 63;
    if (t < 64) {
        ac[t] = acum[(size_t)(bc * 64 + t) * 64 + h];
        dts[t] = dtq[(size_t)(bc * 64 + t) * 64 + h];
    }
    __syncthreads();
    if (t < 64) dec[t] = __expf(ac[63] - ac[t]);
    for (int idx = t; idx < 4096; idx += 256) {
        int s = idx >> 6, p = idx & 63;
        float v = b2f(xb[(size_t)(bc * 64 + s) * 4096 + h * 64 + p]) * dts[s];
        XT[(p << 6) + (s ^ ((p & 7) << 3))] = f2bf(v);
    }
    for (int idx = t; idx < 4096; idx += 256) {
        int l = idx >> 6, s = idx & 63;
        float v = (s <= l) ? __expf(ac[l] - ac[s]) * G[((size_t)bc * 64 + l) * 64 + s] : 0.f;
        Pl[(l << 6) + (s ^ ((l & 7) << 3))] = f2bf(v);
    }
    __syncthreads();                     // dec ready
    for (int idx = t; idx < 8192; idx += 256) {
        int l = idx >> 7, n = idx & 127;
        float v = b2f(Bo[(size_t)(bc * 64 + l) * 128 + n]) * dec[l];
        BTd[(n << 6) + (l ^ ((n & 7) << 3))] = f2bf(v);
    }
    __syncthreads();
    // ---- Y_diag: wave w owns l-rows [16w,16w+16); 4 p-tiles; K=64
    {
        floatx4 accY[4];
        #pragma unroll
        for (int ni = 0; ni < 4; ni++) accY[ni] = (floatx4){0.f, 0.f, 0.f, 0.f};
        int row = (w << 4) + (lane & 15);
        #pragma unroll
        for (int ks = 0; ks < 2; ks++) {
            int k = (ks << 5) + ((lane >> 4) << 3);
            int kx = k ^ ((row & 7) << 3);
            bhalf8 af = *(const bhalf8*)(Pl + (row << 6) + kx);
            #pragma unroll
            for (int ni = 0; ni < 4; ni++) {
                int pr = (ni << 4) + (lane & 15);
                bhalf8 bf = *(const bhalf8*)(XT + (pr << 6) + kx);
                accY[ni] = __builtin_amdgcn_mfma_f32_16x16x32_bf16(af, bf, accY[ni], 0, 0, 0);
            }
        }
        #pragma unroll
        for (int ni = 0; ni < 4; ni++) {
            int col = (ni << 4) + (lane & 15);
            #pragma unroll
            for (int r = 0; r < 4; r++) {
                int l = (w << 4) + ((lane >> 4) << 2) + r;
                y[(size_t)(bc * 64 + l) * 4096 + h * 64 + col] = f2bf(accY[ni][r]);
            }
        }
    }
    // ---- chunk state: wave w owns p-rows [16w,16w+16); 8 n-tiles; K=64
    {
        floatx4 accS[8];
        #pragma unroll
        for (int ni = 0; ni < 8; ni++) accS[ni] = (floatx4){0.f, 0.f, 0.f, 0.f};
        int prow = (w << 4) + (lane & 15);
        #pragma unroll
        for (int ks = 0; ks < 2; ks++) {
            int k = (ks << 5) + ((lane >> 4) << 3);
            int kx = k ^ ((prow & 7) << 3);
            bhalf8 af = *(const bhalf8*)(XT + (prow << 6) + kx);
            #pragma unroll
            for (int ni = 0; ni < 8; ni++) {
                int nr = (ni << 4) + (lane & 15);
                bhalf8 bf = *(const bhalf8*)(BTd + (nr << 6) + kx);
                accS[ni] = __builtin_amdgcn_mfma_f32_16x16x32_bf16(af, bf, accS[ni], 0, 0, 0);
            }
        }
        #pragma unroll
        for (int ni = 0; ni < 8; ni++) {
            int n = (ni << 4) + (lane & 15);
            #pragma unroll
            for (int r = 0; r < 4; r++) {
                int p = (w << 4) + ((lane >> 4) << 2) + r;
                cs[((size_t)(bc * 64 + h) * 64 + p) * 128 + n] = f2bf(accS[ni][r]);
            }
        }
    }
}

// ---------------- in-place chunk-prefix scan over c (bf16 storage, fp32 recur) ----------------
__global__ __launch_bounds__(256) void k_scan(u16* __restrict__ cs, const float* __restrict__ Tc) {
    int bid = blockIdx.x;            // 2*64*32 = 4096
    int bh = bid >> 5, pb = bid & 31;
    int b = bh >> 6, h = bh & 63;
    int pn = pb * 256 + threadIdx.x; // 0..8191
    const float* Tp = Tc + bh * 32;
    size_t stride = (size_t)64 * 8192;
    size_t base = (((size_t)(b * 32) * 64) + h) * 8192 + pn;
    float v[32];
    #pragma unroll
    for (int c = 0; c < 32; c++) v[c] = b2f(cs[base + (size_t)c * stride]);
    float P = 0.f;
    #pragma unroll
    for (int c = 0; c < 32; c++) {
        float tmp = v[c];
        cs[base + (size_t)c * stride] = f2bf(P);
        P = __expf(Tp[c]) * P + tmp;
    }
}

// ---------------- Y_off: y += od[l] * C @ S^T  (MFMA, bf16 RMW) ----------------
__global__ __launch_bounds__(256) void k_yoff(
    const u16* __restrict__ Co, const u16* __restrict__ cs,
    const float* __restrict__ acum, u16* __restrict__ y) {
    int bc = blockIdx.x, h = blockIdx.y;
    __shared__ u16 Cl[8192];   // [l][n], 128-col rows: swz ^((row&15)<<3)
    __shared__ u16 Sl[8192];   // [p][n]
    __shared__ float od[64];
    int t = threadIdx.x, w = t >> 6, lane = t & 63;
    for (int idx = t; idx < 8192; idx += 256) {
        int l = idx >> 7, n = idx & 127;
        Cl[(l << 7) + (n ^ ((l & 15) << 3))] = Co[(size_t)(bc * 64 + l) * 128 + n];
    }
    size_t pbase = ((size_t)bc * 64 + h) * 8192;
    for (int idx = t; idx < 8192; idx += 256) {
        int p = idx >> 7, n = idx & 127;
        Sl[(p << 7) + (n ^ ((p & 15) << 3))] = cs[pbase + idx];
    }
    if (t < 64) od[t] = __expf(acum[(size_t)(bc * 64 + t) * 64 + h]);
    __syncthreads();
    floatx4 acc[4];
    #pragma unroll
    for (int ni = 0; ni < 4; ni++) acc[ni] = (floatx4){0.f, 0.f, 0.f, 0.f};
    int lrow = (w << 4) + (lane & 15);
    #pragma unroll
    for (int ks = 0; ks < 4; ks++) {
        int k = (ks << 5) + ((lane >> 4) << 3);
        int kx = k ^ ((lrow & 15) << 3);
        bhalf8 af = *(const bhalf8*)(Cl + (lrow << 7) + kx);
        #pragma unroll
        for (int ni = 0; ni < 4; ni++) {
            int pr = (ni << 4) + (lane & 15);
            bhalf8 bf = *(const bhalf8*)(Sl + (pr << 7) + kx);
            acc[ni] = __builtin_amdgcn_mfma_f32_16x16x32_bf16(af, bf, acc[ni], 0, 0, 0);
        }
    }
    #pragma unroll
    for (int ni = 0; ni < 4; ni++) {
        int col = (ni << 4) + (lane & 15);
        #pragma unroll
        for (int r = 0; r < 4; r++) {
            int l = (w << 4) + ((lane >> 4) << 2) + r;
            size_t yi = (size_t)(bc * 64 + l) * 4096 + h * 64 + col;
            y[yi] = f2bf(b2f(y[yi]) + od[l] * acc[ni][r]);
        }
    }
}

// ---------------- gating (silu(z)) + D skip + RMSNorm -> bf16 ----------------
__global__ __launch_bounds__(256) void k_norm(
    const u16* __restrict__ y, const u16* __restrict__ x, const u16* __restrict__ z,
    const float* __restrict__ D_param, const float* __restrict__ norm_w,
    u16* __restrict__ ynorm) {
    int row = blockIdx.x;
    int t = threadIdx.x;
    size_t base = (size_t)row * 4096 + (size_t)t * 16;
    float yv[16], xf[16], zf[16];
    {
        uint4 a = ((const uint4*)(y + base))[0];
        uint4 b = ((const uint4*)(y + base))[1];
        unpack2(a.x, yv[0], yv[1]); unpack2(a.y, yv[2], yv[3]);
        unpack2(a.z, yv[4], yv[5]); unpack2(a.w, yv[6], yv[7]);
        unpack2(b.x, yv[8], yv[9]); unpack2(b.y, yv[10], yv[11]);
        unpack2(b.z, yv[12], yv[13]); unpack2(b.w, yv[14], yv[15]);
    }
    {
        uint4 a = ((const uint4*)(x + base))[0];
        uint4 b = ((const uint4*)(x + base))[1];
        unpack2(a.x, xf[0], xf[1]); unpack2(a.y, xf[2], xf[3]);
        unpack2(a.z, xf[4], xf[5]); unpack2(a.w, xf[6], xf[7]);
        unpack2(b.x, xf[8], xf[9]); unpack2(b.y, xf[10], xf[11]);
        unpack2(b.z, xf[12], xf[13]); unpack2(b.w, xf[14], xf[15]);
    }
    {
        uint4 a = ((const uint4*)(z + base))[0];
        uint4 b = ((const uint4*)(z + base))[1];
        unpack2(a.x, zf[0], zf[1]); unpack2(a.y, zf[2], zf[3]);
        unpack2(a.z, zf[4], zf[5]); unpack2(a.w, zf[6], zf[7]);
        unpack2(b.x, zf[8], zf[9]); unpack2(b.y, zf[10], zf[11]);
        unpack2(b.z, zf[12], zf[13]); unpack2(b.w, zf[14], zf[15]);
    }
    float D = D_param[t >> 2];
    float vals[16], ss = 0.f;
    #pragma unroll
    for (int j = 0; j < 16; j++) {
        float v = yv[j] + xf[j] * D;
        float zz = zf[j];
        float yf = v * (zz / (1.f + __expf(-zz)));
        vals[j] = yf;
        ss += yf * yf;
    }
    #pragma unroll
    for (int o = 32; o > 0; o >>= 1) ss += __shfl_down(ss, o, 64);
    __shared__ float red[4];
    if ((t & 63) == 0) red[t >> 6] = ss;
    __syncthreads();
    float tot = red[0] + red[1] + red[2] + red[3];
    float rr = rsqrtf(tot * (1.f / 4096.f) + 1e-5f);
    unsigned o32[8];
    #pragma unroll
    for (int j = 0; j < 8; j++) {
        float lo = vals[2 * j] * rr * norm_w[t * 16 + 2 * j];
        float hi = vals[2 * j + 1] * rr * norm_w[t * 16 + 2 * j + 1];
        o32[j] = (unsigned)f2bf(lo) | ((unsigned)f2bf(hi) << 16);
    }
    uint4 w0, w1;
    w0.x = o32[0]; w0.y = o32[1]; w0.z = o32[2]; w0.w = o32[3];
    w1.x = o32[4]; w1.y = o32[5]; w1.z = o32[6]; w1.w = o32[7];
    ((uint4*)(ynorm + base))[0] = w0;
    ((uint4*)(ynorm + base))[1] = w1;
}

// ---------------- launch ----------------
extern "C" void kernel_launch(void* const* d_in, const int* in_sizes, int n_in,
                              void* d_out, int out_size, void* d_ws, size_t ws_size,
                              hipStream_t stream) {
    const float* u       = (const float*)d_in[0];
    const float* W_in    = (const float*)d_in[1];
    const float* conv_w  = (const float*)d_in[2];
    const float* conv_b  = (const float*)d_in[3];
    const float* dt_bias = (const float*)d_in[4];
    const float* A_log   = (const float*)d_in[5];
    const float* D_param = (const float*)d_in[6];
    const float* norm_w  = (const float*)d_in[7];
    const float* W_out   = (const float*)d_in[8];
    float* out = (float*)d_out;

    // ---- workspace budget (lifetime-aliased) ----
    const size_t REGION = (size_t)134217728;
    size_t need = REGION
                + (size_t)33554432   // zb
                + (size_t)33554432   // xb
                + (size_t)1048576    // Bo
                + (size_t)1048576    // Co
                + (size_t)1048576    // acum
                + (size_t)16384      // Tc
                + (size_t)1048576    // G
                + (size_t)1048576    // dtq
                + (size_t)33554432;  // yb
    if (ws_size < need) return;      // diagnostic: clean absmax fail, no fault

    char* ws = (char*)d_ws;
    // transient region overlays
    u16*   ubf   = (u16*)(ws);
    u16*   WinT  = (u16*)(ws + 16777216);
    u16*   xbc   = (u16*)(ws + 16777216 + 35651584);
    u16*   cs    = (u16*)(ws);
    u16*   WoutT = (u16*)(ws);
    u16*   ynorm = (u16*)(ws + 16777216);
    // persistent
    char* p = ws + REGION;
    u16*   zb    = (u16*)p;            p += 33554432;
    u16*   xb    = (u16*)p;            p += 33554432;
    u16*   Bo    = (u16*)p;            p += 1048576;
    u16*   Co    = (u16*)p;            p += 1048576;
    float* acum  = (float*)p;          p += 1048576;
    float* Tc    = (float*)p;          p += 16384;
    float* G     = (float*)p;          p += 1048576;
    float* dtq   = (float*)p;          p += 1048576;
    u16*   yb    = (u16*)p;            p += 33554432;

    // 1. u -> bf16
    k_f2b4<<<8192, 256, 0, stream>>>(u, ubf, 4096 * 2048 / 4);
    // 2. W_in -> bf16 transposed, padded to 8576 rows (67 x 128-tiles)
    k_transpose_f2b<<<dim3(268, 64), dim3(32, 8), 0, stream>>>(W_in, WinT, 2048, 8512);
    // 3. in_proj GEMM (LDS dbuf) + split/softplus epilogue; plain 2D grid
    gemm_bt<1><<<dim3(67, 32), 256, 0, stream>>>(ubf, WinT, 4096, 8576, 2048,
                                                 nullptr, zb, xbc, dtq, dt_bias);
    // 4. conv + silu + split (x, B, C); 8-row register-ring tiles
    k_conv<<<512, 256, 0, stream>>>(xbc, conv_w, conv_b, xb, Bo, Co);
    // 5. cumsum(A*dt) per chunk + chunk totals
    k_dtprep<<<64, 64, 0, stream>>>(dtq, A_log, acum, Tc);
    // 6. G = C B^T (256 blocks)
    k_G<<<dim3(64, 4), 256, 0, stream>>>(Bo, Co, G);
    // 7. Y_diag + chunk states, MFMA  (xbc dead -> cs overlays region)
    k_diag<<<dim3(64, 64), 256, 0, stream>>>(xb, Bo, G, acum, dtq, yb, cs);
    // 8. chunk-prefix scan (in place, bf16)
    k_scan<<<4096, 256, 0, stream>>>(cs, Tc);
    // 9. Y_off accumulate into yb (MFMA, bf16 RMW)
    k_yoff<<<dim3(64, 64), 256, 0, stream>>>(Co, cs, acum, yb);
    // 10. W_out -> bf16 transposed (cs dead -> WoutT overlays region)
    k_transpose_f2b<<<dim3(64, 128), dim3(32, 8), 0, stream>>>(W_out, WoutT, 4096, 2048);
    // 11. gating + D skip + RMSNorm -> bf16
    k_norm<<<4096, 256, 0, stream>>>(yb, xb, zb, D_param, norm_w, ynorm);
    // 12. out_proj GEMM (LDS dbuf) -> fp32 out; plain 2D grid
    gemm_bt<0><<<dim3(16, 32), 256, 0, stream>>>(ynorm, WoutT, 4096, 2048, 4096,
                                                 out, nullptr, nullptr, nullptr, nullptr);
    (void)in_sizes; (void)n_in; (void)out_size;
}

// Round 12
// 590.207 us; speedup vs baseline: 1.1405x; 1.0293x over previous
//
#include <hip/hip_runtime.h>

typedef unsigned short u16;
typedef __attribute__((ext_vector_type(8))) short bhalf8;   // 8 bf16 in 4 VGPRs
typedef __attribute__((ext_vector_type(4))) float floatx4;

// ---------------- helpers ----------------
__device__ __forceinline__ u16 f2bf(float f) {
    union { float f; unsigned u; } v; v.f = f;
    unsigned u = v.u;
    unsigned r = u + 0x7fffu + ((u >> 16) & 1u);
    return (u16)(r >> 16);
}
__device__ __forceinline__ float b2f(u16 h) {
    union { unsigned u; float f; } v; v.u = ((unsigned)h) << 16; return v.f;
}
__device__ __forceinline__ void unpack2(unsigned u, float& lo, float& hi) {
    union { unsigned u; float f; } a, b;
    a.u = u << 16; b.u = u & 0xffff0000u;
    lo = a.f; hi = b.f;
}
__device__ __forceinline__ void load_lds16(const void* g, void* l) {
    __builtin_amdgcn_global_load_lds(
        (const __attribute__((address_space(1))) unsigned int*)g,
        (__attribute__((address_space(3))) unsigned int*)l, 16, 0, 0);
}

// ---------------- fp32 -> bf16 (vector) ----------------
__global__ void k_f2b4(const float* __restrict__ in, u16* __restrict__ out, int n4) {
    int i = blockIdx.x * 256 + threadIdx.x;
    if (i < n4) {
        float4 v = ((const float4*)in)[i];
        unsigned lo = (unsigned)f2bf(v.x) | ((unsigned)f2bf(v.y) << 16);
        unsigned hi = (unsigned)f2bf(v.z) | ((unsigned)f2bf(v.w) << 16);
        ((uint2*)out)[i] = make_uint2(lo, hi);
    }
}

// ---------------- transpose fp32[K][N] -> bf16[Npad][K] ----------------
__global__ void k_transpose_f2b(const float* __restrict__ W, u16* __restrict__ Wt,
                                int K, int N) {
    __shared__ float tile[32][33];
    int nt = blockIdx.x * 32, kt = blockIdx.y * 32;
    int tx = threadIdx.x, ty = threadIdx.y;
    #pragma unroll
    for (int r = 0; r < 32; r += 8) {
        int k = kt + ty + r, n = nt + tx;
        tile[ty + r][tx] = (n < N && k < K) ? W[(size_t)k * N + n] : 0.f;
    }
    __syncthreads();
    #pragma unroll
    for (int r = 0; r < 32; r += 8) {
        int n = nt + ty + r, k = kt + tx;
        Wt[(size_t)n * K + k] = f2bf(tile[tx][ty + r]);
    }
}

// ---------------- 128x128 bf16 MFMA GEMM, LDS double-buffered (r9-frozen) ----------------
// + T5 setprio around MFMA cluster (2 independent blocks/CU at different
//   phases -> scheduler role-diversity; m191-regime, not m190 lockstep).
template <int EPI>
__global__ __launch_bounds__(256) void gemm_bt(
    const u16* __restrict__ A, const u16* __restrict__ Bt, int M, int N, int K,
    float* __restrict__ outF,
    u16* __restrict__ zb, u16* __restrict__ xbc, float* __restrict__ dtq,
    const float* __restrict__ dt_bias) {
    __shared__ u16 As[2 * 8192];   // 2 x 128x64 bf16
    __shared__ u16 Bs[2 * 8192];
    int t = threadIdx.x;
    int w = t >> 6, lane = t & 63;
    int m0 = blockIdx.y * 128, n0 = blockIdx.x * 128;
    int wm = (w >> 1) * 64, wn = (w & 1) * 64;
    floatx4 acc[4][4];
    #pragma unroll
    for (int i = 0; i < 4; i++)
        #pragma unroll
        for (int j = 0; j < 4; j++) acc[i][j] = (floatx4){0.f, 0.f, 0.f, 0.f};

    const int nt = K >> 6;
    const int byte0 = (w * 4) * 1024 + lane * 16;

    auto stage = [&](int sel, int k0) {
        #pragma unroll
        for (int i = 0; i < 4; i++) {
            int byte = byte0 + i * 1024;
            int row = byte >> 7;
            int colb = (byte & 127) ^ ((row & 7) << 4);
            load_lds16(A + (size_t)(m0 + row) * K + k0 + (colb >> 1),
                       (char*)As + sel * 16384 + byte);
            load_lds16(Bt + (size_t)(n0 + row) * K + k0 + (colb >> 1),
                       (char*)Bs + sel * 16384 + byte);
        }
    };

    stage(0, 0);
    __syncthreads();
    int cur = 0;
    for (int kt = 0; kt < nt; ++kt) {
        if (kt + 1 < nt) stage(cur ^ 1, (kt + 1) << 6);
        const u16* Ab = As + cur * 8192;
        const u16* Bb = Bs + cur * 8192;
        #pragma unroll
        for (int ks = 0; ks < 2; ks++) {
            int kk = ks * 32 + ((lane >> 4) << 3);
            bhalf8 af[4], bf[4];
            #pragma unroll
            for (int mi = 0; mi < 4; mi++) {
                int row = wm + mi * 16 + (lane & 15);
                int idx = (row * 64 + kk) ^ ((row & 7) << 3);
                af[mi] = *(const bhalf8*)(Ab + idx);
            }
            #pragma unroll
            for (int ni = 0; ni < 4; ni++) {
                int col = wn + ni * 16 + (lane & 15);
                int idx = (col * 64 + kk) ^ ((col & 7) << 3);
                bf[ni] = *(const bhalf8*)(Bb + idx);
            }
            __builtin_amdgcn_s_setprio(1);
            #pragma unroll
            for (int mi = 0; mi < 4; mi++)
                #pragma unroll
                for (int ni = 0; ni < 4; ni++)
                    acc[mi][ni] = __builtin_amdgcn_mfma_f32_16x16x32_bf16(
                        af[mi], bf[ni], acc[mi][ni], 0, 0, 0);
            __builtin_amdgcn_s_setprio(0);
        }
        __syncthreads();
        cur ^= 1;
    }
    #pragma unroll
    for (int mi = 0; mi < 4; mi++) {
        #pragma unroll
        for (int ni = 0; ni < 4; ni++) {
            floatx4 v = acc[mi][ni];
            int col = n0 + wn + ni * 16 + (lane & 15);
            #pragma unroll
            for (int r = 0; r < 4; r++) {
                int row = m0 + wm + mi * 16 + ((lane >> 4) << 2) + r;
                float val = v[r];
                if (EPI == 0) {
                    outF[(size_t)row * N + col] = val;
                } else {
                    if (col < 4096) {
                        zb[(size_t)row * 4096 + col] = f2bf(val);
                    } else if (col < 8448) {
                        xbc[(size_t)row * 4352 + (col - 4096)] = f2bf(val);
                    } else if (col < 8512) {
                        int h = col - 8448;
                        float xv = val + dt_bias[h];
                        float sp = (xv > 20.f) ? xv : log1pf(__expf(xv));
                        dtq[(size_t)row * 64 + h] = sp;
                    }
                }
            }
        }
    }
}

// ---------------- causal depthwise conv(4) + silu + split (8-row tiles, vec2) ----------------
// 2 channels/thread via packed uint loads/stores (splits at 4096/4224 are
// even -> a pair never straddles an output boundary).
__global__ __launch_bounds__(256) void k_conv(
    const u16* __restrict__ xbc, const float* __restrict__ conv_w,
    const float* __restrict__ conv_b,
    u16* __restrict__ x, u16* __restrict__ Bo, u16* __restrict__ Co) {
    int bid = blockIdx.x;            // 512 = 2 b * 256 l-tiles
    int b = bid >> 8, lt = bid & 255;
    int l0 = lt * 8;
    const unsigned* xb32 = (const unsigned*)xbc;
    size_t rb = (size_t)(b * 2048) * 2176;
    for (int cp = threadIdx.x; cp < 2176; cp += 256) {
        int ch = cp << 1;
        const float4* wp = (const float4*)(conv_w + ch * 4);
        float4 wA = wp[0], wB = wp[1];
        float bcA = conv_b[ch], bcB = conv_b[ch + 1];
        float h0A = 0.f, h1A = 0.f, h2A = 0.f, h0B = 0.f, h1B = 0.f, h2B = 0.f;
        if (l0 >= 3) unpack2(xb32[rb + (size_t)(l0 - 3) * 2176 + cp], h0A, h0B);
        if (l0 >= 2) unpack2(xb32[rb + (size_t)(l0 - 2) * 2176 + cp], h1A, h1B);
        if (l0 >= 1) unpack2(xb32[rb + (size_t)(l0 - 1) * 2176 + cp], h2A, h2B);
        #pragma unroll
        for (int i = 0; i < 8; i++) {
            int l = l0 + i;
            float xcA, xcB;
            unpack2(xb32[rb + (size_t)l * 2176 + cp], xcA, xcB);
            float aA = bcA + wA.x * h0A + wA.y * h1A + wA.z * h2A + wA.w * xcA;
            float aB = bcB + wB.x * h0B + wB.y * h1B + wB.z * h2B + wB.w * xcB;
            float vA = aA / (1.f + __expf(-aA));   // silu
            float vB = aB / (1.f + __expf(-aB));
            int row = b * 2048 + l;
            unsigned pk = (unsigned)f2bf(vA) | ((unsigned)f2bf(vB) << 16);
            if (ch < 4096) {
                ((unsigned*)x)[(size_t)row * 2048 + cp] = pk;
            } else if (ch < 4224) {
                ((unsigned*)Bo)[(size_t)row * 64 + (cp - 2048)] = pk;
            } else {
                ((unsigned*)Co)[(size_t)row * 64 + (cp - 2112)] = pk;
            }
            h0A = h1A; h1A = h2A; h2A = xcA;
            h0B = h1B; h1B = h2B; h2B = xcB;
        }
    }
}

// ---------------- per-chunk cumsum of A*dt + chunk totals ----------------
__global__ void k_dtprep(const float* __restrict__ dtq, const float* __restrict__ A_log,
                         float* __restrict__ acum, float* __restrict__ Tc) {
    int bc = blockIdx.x;     // b*32 + c
    int h = threadIdx.x;     // 64 threads
    float A = -__expf(A_log[h]);
    float s = 0.f;
    #pragma unroll
    for (int l = 0; l < 64; l++) {
        int row = bc * 64 + l;
        s += A * dtq[row * 64 + h];
        acum[(size_t)row * 64 + h] = s;
    }
    int b = bc >> 5, c = bc & 31;
    Tc[(b * 64 + h) * 32 + c] = s;
}

// ---------------- G = C * B^T per (b,c); 256 blocks (16 l-rows each) ----------------
__global__ __launch_bounds__(256) void k_G(const u16* __restrict__ Bo, const u16* __restrict__ Co,
                                           float* __restrict__ G) {
    int bc = blockIdx.x;
    int lq = blockIdx.y;             // 0..3, 16 l-rows per block
    __shared__ float BsT[128][68];   // [n][s]
    __shared__ float Cs[16][132];    // [l][n]
    int t = threadIdx.x;
    for (int idx = t; idx < 64 * 128; idx += 256) {
        int r = idx >> 7, n = idx & 127;
        BsT[n][r] = b2f(Bo[(size_t)(bc * 64 + r) * 128 + n]);
    }
    for (int idx = t; idx < 16 * 128; idx += 256) {
        int r = idx >> 7, n = idx & 127;
        Cs[r][n] = b2f(Co[(size_t)(bc * 64 + lq * 16 + r) * 128 + n]);
    }
    __syncthreads();
    int lr = t >> 4, sq = t & 15;    // l-row 0..15, s-quad 0..15 (4 s each)
    int l = lq * 16 + lr;
    float a[4] = {0.f, 0.f, 0.f, 0.f};
    for (int n = 0; n < 128; n++) {
        float cv = Cs[lr][n];
        const float4* bp = (const float4*)&BsT[n][sq * 4];
        float4 b0 = bp[0];
        a[0] += cv * b0.x; a[1] += cv * b0.y; a[2] += cv * b0.z; a[3] += cv * b0.w;
    }
    size_t gb = ((size_t)bc * 64 + l) * 64 + sq * 4;
    #pragma unroll
    for (int i = 0; i < 4; i++) G[gb + i] = a[i];
}

// ---------------- Y_diag + chunk states per (b,c,h), MFMA ----------------
__global__ __launch_bounds__(256) void k_diag(
    const u16* __restrict__ xb, const u16* __restrict__ Bo,
    const float* __restrict__ G, const float* __restrict__ acum,
    const float* __restrict__ dtq,
    u16* __restrict__ y, u16* __restrict__ cs) {
    int bc = blockIdx.x, h = blockIdx.y;
    __shared__ u16 XT[4096];    // [p][s] = x[s][p]*dt[s]
    __shared__ u16 Pl[4096];    // [l][s]
    __shared__ u16 BTd[8192];   // [n][l] = B[l][n]*dec[l]
    __shared__ float ac[64], dec[64], dts[64];
    int t = threadIdx.x, w = t >> 6, lane = t & 63;
    if (t < 64) {
        ac[t] = acum[(size_t)(bc * 64 + t) * 64 + h];
        dts[t] = dtq[(size_t)(bc * 64 + t) * 64 + h];
    }
    __syncthreads();
    if (t < 64) dec[t] = __expf(ac[63] - ac[t]);
    for (int idx = t; idx < 4096; idx += 256) {
        int s = idx >> 6, p = idx & 63;
        float v = b2f(xb[(size_t)(bc * 64 + s) * 4096 + h * 64 + p]) * dts[s];
        XT[(p << 6) + (s ^ ((p & 7) << 3))] = f2bf(v);
    }
    for (int idx = t; idx < 4096; idx += 256) {
        int l = idx >> 6, s = idx & 63;
        float v = (s <= l) ? __expf(ac[l] - ac[s]) * G[((size_t)bc * 64 + l) * 64 + s] : 0.f;
        Pl[(l << 6) + (s ^ ((l & 7) << 3))] = f2bf(v);
    }
    __syncthreads();                     // dec ready
    for (int idx = t; idx < 8192; idx += 256) {
        int l = idx >> 7, n = idx & 127;
        float v = b2f(Bo[(size_t)(bc * 64 + l) * 128 + n]) * dec[l];
        BTd[(n << 6) + (l ^ ((n & 7) << 3))] = f2bf(v);
    }
    __syncthreads();
    // ---- Y_diag: wave w owns l-rows [16w,16w+16); 4 p-tiles; K=64
    {
        floatx4 accY[4];
        #pragma unroll
        for (int ni = 0; ni < 4; ni++) accY[ni] = (floatx4){0.f, 0.f, 0.f, 0.f};
        int row = (w << 4) + (lane & 15);
        #pragma unroll
        for (int ks = 0; ks < 2; ks++) {
            int k = (ks << 5) + ((lane >> 4) << 3);
            int kx = k ^ ((row & 7) << 3);
            bhalf8 af = *(const bhalf8*)(Pl + (row << 6) + kx);
            #pragma unroll
            for (int ni = 0; ni < 4; ni++) {
                int pr = (ni << 4) + (lane & 15);
                bhalf8 bf = *(const bhalf8*)(XT + (pr << 6) + kx);
                accY[ni] = __builtin_amdgcn_mfma_f32_16x16x32_bf16(af, bf, accY[ni], 0, 0, 0);
            }
        }
        #pragma unroll
        for (int ni = 0; ni < 4; ni++) {
            int col = (ni << 4) + (lane & 15);
            #pragma unroll
            for (int r = 0; r < 4; r++) {
                int l = (w << 4) + ((lane >> 4) << 2) + r;
                y[(size_t)(bc * 64 + l) * 4096 + h * 64 + col] = f2bf(accY[ni][r]);
            }
        }
    }
    // ---- chunk state: wave w owns p-rows [16w,16w+16); 8 n-tiles; K=64
    {
        floatx4 accS[8];
        #pragma unroll
        for (int ni = 0; ni < 8; ni++) accS[ni] = (floatx4){0.f, 0.f, 0.f, 0.f};
        int prow = (w << 4) + (lane & 15);
        #pragma unroll
        for (int ks = 0; ks < 2; ks++) {
            int k = (ks << 5) + ((lane >> 4) << 3);
            int kx = k ^ ((prow & 7) << 3);
            bhalf8 af = *(const bhalf8*)(XT + (prow << 6) + kx);
            #pragma unroll
            for (int ni = 0; ni < 8; ni++) {
                int nr = (ni << 4) + (lane & 15);
                bhalf8 bf = *(const bhalf8*)(BTd + (nr << 6) + kx);
                accS[ni] = __builtin_amdgcn_mfma_f32_16x16x32_bf16(af, bf, accS[ni], 0, 0, 0);
            }
        }
        #pragma unroll
        for (int ni = 0; ni < 8; ni++) {
            int n = (ni << 4) + (lane & 15);
            #pragma unroll
            for (int r = 0; r < 4; r++) {
                int p = (w << 4) + ((lane >> 4) << 2) + r;
                cs[((size_t)(bc * 64 + h) * 64 + p) * 128 + n] = f2bf(accS[ni][r]);
            }
        }
    }
}

// ---------------- in-place chunk-prefix scan over c (bf16 storage, fp32 recur) ----------------
__global__ __launch_bounds__(256) void k_scan(u16* __restrict__ cs, const float* __restrict__ Tc) {
    int bid = blockIdx.x;            // 2*64*32 = 4096
    int bh = bid >> 5, pb = bid & 31;
    int b = bh >> 6, h = bh & 63;
    int pn = pb * 256 + threadIdx.x; // 0..8191
    const float* Tp = Tc + bh * 32;
    size_t stride = (size_t)64 * 8192;
    size_t base = (((size_t)(b * 32) * 64) + h) * 8192 + pn;
    float v[32];
    #pragma unroll
    for (int c = 0; c < 32; c++) v[c] = b2f(cs[base + (size_t)c * stride]);
    float P = 0.f;
    #pragma unroll
    for (int c = 0; c < 32; c++) {
        float tmp = v[c];
        cs[base + (size_t)c * stride] = f2bf(P);
        P = __expf(Tp[c]) * P + tmp;
    }
}

// ---------------- Y_off: y += od[l] * C @ S^T  (MFMA, bf16 RMW; 2 h/block) ----------------
__global__ __launch_bounds__(256) void k_yoff(
    const u16* __restrict__ Co, const u16* __restrict__ cs,
    const float* __restrict__ acum, u16* __restrict__ y) {
    int bc = blockIdx.x;
    int h0 = blockIdx.y << 1;          // handles h0, h0+1 (C staged once)
    __shared__ u16 Cl[8192];   // [l][n], 128-col rows: swz ^((row&15)<<3)
    __shared__ u16 Sl[2][8192];
    __shared__ float od[2][64];
    int t = threadIdx.x, w = t >> 6, lane = t & 63;
    for (int idx = t; idx < 8192; idx += 256) {
        int l = idx >> 7, n = idx & 127;
        Cl[(l << 7) + (n ^ ((l & 15) << 3))] = Co[(size_t)(bc * 64 + l) * 128 + n];
    }
    #pragma unroll
    for (int j = 0; j < 2; j++) {
        size_t pbase = ((size_t)bc * 64 + (h0 + j)) * 8192;
        for (int idx = t; idx < 8192; idx += 256) {
            int p = idx >> 7, n = idx & 127;
            Sl[j][(p << 7) + (n ^ ((p & 15) << 3))] = cs[pbase + idx];
        }
    }
    if (t < 128) {
        int j = t >> 6, l = t & 63;
        od[j][l] = __expf(acum[(size_t)(bc * 64 + l) * 64 + h0 + j]);
    }
    __syncthreads();
    int lrow = (w << 4) + (lane & 15);
    #pragma unroll
    for (int j = 0; j < 2; j++) {
        floatx4 acc[4];
        #pragma unroll
        for (int ni = 0; ni < 4; ni++) acc[ni] = (floatx4){0.f, 0.f, 0.f, 0.f};
        #pragma unroll
        for (int ks = 0; ks < 4; ks++) {
            int k = (ks << 5) + ((lane >> 4) << 3);
            int kx = k ^ ((lrow & 15) << 3);
            bhalf8 af = *(const bhalf8*)(Cl + (lrow << 7) + kx);
            #pragma unroll
            for (int ni = 0; ni < 4; ni++) {
                int pr = (ni << 4) + (lane & 15);
                bhalf8 bf = *(const bhalf8*)(Sl[j] + (pr << 7) + kx);
                acc[ni] = __builtin_amdgcn_mfma_f32_16x16x32_bf16(af, bf, acc[ni], 0, 0, 0);
            }
        }
        #pragma unroll
        for (int ni = 0; ni < 4; ni++) {
            int col = (ni << 4) + (lane & 15);
            #pragma unroll
            for (int r = 0; r < 4; r++) {
                int l = (w << 4) + ((lane >> 4) << 2) + r;
                size_t yi = (size_t)(bc * 64 + l) * 4096 + (h0 + j) * 64 + col;
                y[yi] = f2bf(b2f(y[yi]) + od[j][l] * acc[ni][r]);
            }
        }
    }
}

// ---------------- gating (silu(z)) + D skip + RMSNorm -> bf16 ----------------
__global__ __launch_bounds__(256) void k_norm(
    const u16* __restrict__ y, const u16* __restrict__ x, const u16* __restrict__ z,
    const float* __restrict__ D_param, const float* __restrict__ norm_w,
    u16* __restrict__ ynorm) {
    int row = blockIdx.x;
    int t = threadIdx.x;
    size_t base = (size_t)row * 4096 + (size_t)t * 16;
    float yv[16], xf[16], zf[16];
    {
        uint4 a = ((const uint4*)(y + base))[0];
        uint4 b = ((const uint4*)(y + base))[1];
        unpack2(a.x, yv[0], yv[1]); unpack2(a.y, yv[2], yv[3]);
        unpack2(a.z, yv[4], yv[5]); unpack2(a.w, yv[6], yv[7]);
        unpack2(b.x, yv[8], yv[9]); unpack2(b.y, yv[10], yv[11]);
        unpack2(b.z, yv[12], yv[13]); unpack2(b.w, yv[14], yv[15]);
    }
    {
        uint4 a = ((const uint4*)(x + base))[0];
        uint4 b = ((const uint4*)(x + base))[1];
        unpack2(a.x, xf[0], xf[1]); unpack2(a.y, xf[2], xf[3]);
        unpack2(a.z, xf[4], xf[5]); unpack2(a.w, xf[6], xf[7]);
        unpack2(b.x, xf[8], xf[9]); unpack2(b.y, xf[10], xf[11]);
        unpack2(b.z, xf[12], xf[13]); unpack2(b.w, xf[14], xf[15]);
    }
    {
        uint4 a = ((const uint4*)(z + base))[0];
        uint4 b = ((const uint4*)(z + base))[1];
        unpack2(a.x, zf[0], zf[1]); unpack2(a.y, zf[2], zf[3]);
        unpack2(a.z, zf[4], zf[5]); unpack2(a.w, zf[6], zf[7]);
        unpack2(b.x, zf[8], zf[9]); unpack2(b.y, zf[10], zf[11]);
        unpack2(b.z, zf[12], zf[13]); unpack2(b.w, zf[14], zf[15]);
    }
    float D = D_param[t >> 2];
    float vals[16], ss = 0.f;
    #pragma unroll
    for (int j = 0; j < 16; j++) {
        float v = yv[j] + xf[j] * D;
        float zz = zf[j];
        float yf = v * (zz / (1.f + __expf(-zz)));
        vals[j] = yf;
        ss += yf * yf;
    }
    #pragma unroll
    for (int o = 32; o > 0; o >>= 1) ss += __shfl_down(ss, o, 64);
    __shared__ float red[4];
    if ((t & 63) == 0) red[t >> 6] = ss;
    __syncthreads();
    float tot = red[0] + red[1] + red[2] + red[3];
    float rr = rsqrtf(tot * (1.f / 4096.f) + 1e-5f);
    unsigned o32[8];
    #pragma unroll
    for (int j = 0; j < 8; j++) {
        float lo = vals[2 * j] * rr * norm_w[t * 16 + 2 * j];
        float hi = vals[2 * j + 1] * rr * norm_w[t * 16 + 2 * j + 1];
        o32[j] = (unsigned)f2bf(lo) | ((unsigned)f2bf(hi) << 16);
    }
    uint4 w0, w1;
    w0.x = o32[0]; w0.y = o32[1]; w0.z = o32[2]; w0.w = o32[3];
    w1.x = o32[4]; w1.y = o32[5]; w1.z = o32[6]; w1.w = o32[7];
    ((uint4*)(ynorm + base))[0] = w0;
    ((uint4*)(ynorm + base))[1] = w1;
}

// ---------------- launch ----------------
extern "C" void kernel_launch(void* const* d_in, const int* in_sizes, int n_in,
                              void* d_out, int out_size, void* d_ws, size_t ws_size,
                              hipStream_t stream) {
    const float* u       = (const float*)d_in[0];
    const float* W_in    = (const float*)d_in[1];
    const float* conv_w  = (const float*)d_in[2];
    const float* conv_b  = (const float*)d_in[3];
    const float* dt_bias = (const float*)d_in[4];
    const float* A_log   = (const float*)d_in[5];
    const float* D_param = (const float*)d_in[6];
    const float* norm_w  = (const float*)d_in[7];
    const float* W_out   = (const float*)d_in[8];
    float* out = (float*)d_out;

    // ---- workspace budget (lifetime-aliased) ----
    const size_t REGION = (size_t)134217728;
    size_t need = REGION
                + (size_t)33554432   // zb
                + (size_t)33554432   // xb
                + (size_t)1048576    // Bo
                + (size_t)1048576    // Co
                + (size_t)1048576    // acum
                + (size_t)16384      // Tc
                + (size_t)1048576    // G
                + (size_t)1048576    // dtq
                + (size_t)33554432;  // yb
    if (ws_size < need) return;      // diagnostic: clean absmax fail, no fault

    char* ws = (char*)d_ws;
    // transient region overlays
    u16*   ubf   = (u16*)(ws);
    u16*   WinT  = (u16*)(ws + 16777216);
    u16*   xbc   = (u16*)(ws + 16777216 + 35651584);
    u16*   cs    = (u16*)(ws);
    u16*   WoutT = (u16*)(ws);
    u16*   ynorm = (u16*)(ws + 16777216);
    // persistent
    char* p = ws + REGION;
    u16*   zb    = (u16*)p;            p += 33554432;
    u16*   xb    = (u16*)p;            p += 33554432;
    u16*   Bo    = (u16*)p;            p += 1048576;
    u16*   Co    = (u16*)p;            p += 1048576;
    float* acum  = (float*)p;          p += 1048576;
    float* Tc    = (float*)p;          p += 16384;
    float* G     = (float*)p;          p += 1048576;
    float* dtq   = (float*)p;          p += 1048576;
    u16*   yb    = (u16*)p;            p += 33554432;

    // 1. u -> bf16
    k_f2b4<<<8192, 256, 0, stream>>>(u, ubf, 4096 * 2048 / 4);
    // 2. W_in -> bf16 transposed, padded to 8576 rows (67 x 128-tiles)
    k_transpose_f2b<<<dim3(268, 64), dim3(32, 8), 0, stream>>>(W_in, WinT, 2048, 8512);
    // 3. in_proj GEMM (LDS dbuf + setprio) + split/softplus epilogue
    gemm_bt<1><<<dim3(67, 32), 256, 0, stream>>>(ubf, WinT, 4096, 8576, 2048,
                                                 nullptr, zb, xbc, dtq, dt_bias);
    // 4. conv + silu + split (x, B, C); 8-row register-ring, 2 ch/thread
    k_conv<<<512, 256, 0, stream>>>(xbc, conv_w, conv_b, xb, Bo, Co);
    // 5. cumsum(A*dt) per chunk + chunk totals
    k_dtprep<<<64, 64, 0, stream>>>(dtq, A_log, acum, Tc);
    // 6. G = C B^T (256 blocks)
    k_G<<<dim3(64, 4), 256, 0, stream>>>(Bo, Co, G);
    // 7. Y_diag + chunk states, MFMA  (xbc dead -> cs overlays region)
    k_diag<<<dim3(64, 64), 256, 0, stream>>>(xb, Bo, G, acum, dtq, yb, cs);
    // 8. chunk-prefix scan (in place, bf16)
    k_scan<<<4096, 256, 0, stream>>>(cs, Tc);
    // 9. Y_off accumulate into yb (MFMA, bf16 RMW; 2 h per block)
    k_yoff<<<dim3(64, 32), 256, 0, stream>>>(Co, cs, acum, yb);
    // 10. W_out -> bf16 transposed (cs dead -> WoutT overlays region)
    k_transpose_f2b<<<dim3(64, 128), dim3(32, 8), 0, stream>>>(W_out, WoutT, 4096, 2048);
    // 11. gating + D skip + RMSNorm -> bf16
    k_norm<<<4096, 256, 0, stream>>>(yb, xb, zb, D_param, norm_w, ynorm);
    // 12. out_proj GEMM (LDS dbuf + setprio) -> fp32 out
    gemm_bt<0><<<dim3(16, 32), 256, 0, stream>>>(ynorm, WoutT, 4096, 2048, 4096,
                                                 out, nullptr, nullptr, nullptr, nullptr);
    (void)in_sizes; (void)n_in; (void)out_size;
}

// Round 13
// 588.296 us; speedup vs baseline: 1.1442x; 1.0032x over previous
//
#include <hip/hip_runtime.h>

typedef unsigned short u16;
typedef __attribute__((ext_vector_type(8))) short bhalf8;   // 8 bf16 in 4 VGPRs
typedef __attribute__((ext_vector_type(4))) float floatx4;

// ---------------- helpers ----------------
__device__ __forceinline__ u16 f2bf(float f) {
    union { float f; unsigned u; } v; v.f = f;
    unsigned u = v.u;
    unsigned r = u + 0x7fffu + ((u >> 16) & 1u);
    return (u16)(r >> 16);
}
__device__ __forceinline__ float b2f(u16 h) {
    union { unsigned u; float f; } v; v.u = ((unsigned)h) << 16; return v.f;
}
__device__ __forceinline__ void unpack2(unsigned u, float& lo, float& hi) {
    union { unsigned u; float f; } a, b;
    a.u = u << 16; b.u = u & 0xffff0000u;
    lo = a.f; hi = b.f;
}
__device__ __forceinline__ void load_lds16(const void* g, void* l) {
    __builtin_amdgcn_global_load_lds(
        (const __attribute__((address_space(1))) unsigned int*)g,
        (__attribute__((address_space(3))) unsigned int*)l, 16, 0, 0);
}

// ---------------- fp32 -> bf16 (vector) ----------------
__global__ void k_f2b4(const float* __restrict__ in, u16* __restrict__ out, int n4) {
    int i = blockIdx.x * 256 + threadIdx.x;
    if (i < n4) {
        float4 v = ((const float4*)in)[i];
        unsigned lo = (unsigned)f2bf(v.x) | ((unsigned)f2bf(v.y) << 16);
        unsigned hi = (unsigned)f2bf(v.z) | ((unsigned)f2bf(v.w) << 16);
        ((uint2*)out)[i] = make_uint2(lo, hi);
    }
}

// ---------------- transpose fp32[K][N] -> bf16[Npad][K] ----------------
__global__ void k_transpose_f2b(const float* __restrict__ W, u16* __restrict__ Wt,
                                int K, int N) {
    __shared__ float tile[32][33];
    int nt = blockIdx.x * 32, kt = blockIdx.y * 32;
    int tx = threadIdx.x, ty = threadIdx.y;
    #pragma unroll
    for (int r = 0; r < 32; r += 8) {
        int k = kt + ty + r, n = nt + tx;
        tile[ty + r][tx] = (n < N && k < K) ? W[(size_t)k * N + n] : 0.f;
    }
    __syncthreads();
    #pragma unroll
    for (int r = 0; r < 32; r += 8) {
        int n = nt + ty + r, k = kt + tx;
        Wt[(size_t)n * K + k] = f2bf(tile[tx][ty + r]);
    }
}

// ---------------- 128x128 bf16 MFMA GEMM, LDS dbuf, BK=32 ----------------
// r9 structure with BK 64->32: LDS 64->32KB => 5 blocks/CU (was 2) for
// latency-hiding TLP.  64B LDS rows: source pre-swizzle colb^=((row>>1)&3)<<4,
// read kk^(((row>>1)&3)<<3) -> 16-lane fragment groups span 8 distinct 16B
// bank-groups (2-way aliasing = free, m136).  Accumulation order over K is
// unchanged (ascending 32-chunks) -> bitwise-identical results.
template <int EPI>
__global__ __launch_bounds__(256) void gemm_bt(
    const u16* __restrict__ A, const u16* __restrict__ Bt, int M, int N, int K,
    float* __restrict__ outF,
    u16* __restrict__ zb, u16* __restrict__ xbc, float* __restrict__ dtq,
    const float* __restrict__ dt_bias) {
    __shared__ u16 As[2 * 4096];   // 2 x 128x32 bf16 (8KB each)
    __shared__ u16 Bs[2 * 4096];
    int t = threadIdx.x;
    int w = t >> 6, lane = t & 63;
    int m0 = blockIdx.y * 128, n0 = blockIdx.x * 128;
    int wm = (w >> 1) * 64, wn = (w & 1) * 64;
    floatx4 acc[4][4];
    #pragma unroll
    for (int i = 0; i < 4; i++)
        #pragma unroll
        for (int j = 0; j < 4; j++) acc[i][j] = (floatx4){0.f, 0.f, 0.f, 0.f};

    const int nt = K >> 5;
    const int byte0 = (w * 2) * 1024 + lane * 16;

    auto stage = [&](int sel, int k0) {
        #pragma unroll
        for (int i = 0; i < 2; i++) {
            int byte = byte0 + i * 1024;
            int row = byte >> 6;                              // 64B per 32-col row
            int colb = (byte & 63) ^ (((row >> 1) & 3) << 4); // source pre-swizzle
            load_lds16(A + (size_t)(m0 + row) * K + k0 + (colb >> 1),
                       (char*)As + sel * 8192 + byte);
            load_lds16(Bt + (size_t)(n0 + row) * K + k0 + (colb >> 1),
                       (char*)Bs + sel * 8192 + byte);
        }
    };

    stage(0, 0);
    __syncthreads();
    int cur = 0;
    for (int kt = 0; kt < nt; ++kt) {
        if (kt + 1 < nt) stage(cur ^ 1, (kt + 1) << 5);
        const u16* Ab = As + cur * 4096;
        const u16* Bb = Bs + cur * 4096;
        const int kk = (lane >> 4) << 3;                      // 0,8,16,24
        bhalf8 af[4], bf[4];
        #pragma unroll
        for (int mi = 0; mi < 4; mi++) {
            int row = wm + mi * 16 + (lane & 15);
            int idx = (row << 5) + (kk ^ (((row >> 1) & 3) << 3));  // read swizzle
            af[mi] = *(const bhalf8*)(Ab + idx);
        }
        #pragma unroll
        for (int ni = 0; ni < 4; ni++) {
            int col = wn + ni * 16 + (lane & 15);
            int idx = (col << 5) + (kk ^ (((col >> 1) & 3) << 3));
            bf[ni] = *(const bhalf8*)(Bb + idx);
        }
        __builtin_amdgcn_s_setprio(1);
        #pragma unroll
        for (int mi = 0; mi < 4; mi++)
            #pragma unroll
            for (int ni = 0; ni < 4; ni++)
                acc[mi][ni] = __builtin_amdgcn_mfma_f32_16x16x32_bf16(
                    af[mi], bf[ni], acc[mi][ni], 0, 0, 0);
        __builtin_amdgcn_s_setprio(0);
        __syncthreads();
        cur ^= 1;
    }
    #pragma unroll
    for (int mi = 0; mi < 4; mi++) {
        #pragma unroll
        for (int ni = 0; ni < 4; ni++) {
            floatx4 v = acc[mi][ni];
            int col = n0 + wn + ni * 16 + (lane & 15);
            #pragma unroll
            for (int r = 0; r < 4; r++) {
                int row = m0 + wm + mi * 16 + ((lane >> 4) << 2) + r;
                float val = v[r];
                if (EPI == 0) {
                    outF[(size_t)row * N + col] = val;
                } else {
                    if (col < 4096) {
                        zb[(size_t)row * 4096 + col] = f2bf(val);
                    } else if (col < 8448) {
                        xbc[(size_t)row * 4352 + (col - 4096)] = f2bf(val);
                    } else if (col < 8512) {
                        int h = col - 8448;
                        float xv = val + dt_bias[h];
                        float sp = (xv > 20.f) ? xv : log1pf(__expf(xv));
                        dtq[(size_t)row * 64 + h] = sp;
                    }
                }
            }
        }
    }
}

// ---------------- causal depthwise conv(4) + silu + split (8-row tiles, vec2) ----------------
__global__ __launch_bounds__(256) void k_conv(
    const u16* __restrict__ xbc, const float* __restrict__ conv_w,
    const float* __restrict__ conv_b,
    u16* __restrict__ x, u16* __restrict__ Bo, u16* __restrict__ Co) {
    int bid = blockIdx.x;            // 512 = 2 b * 256 l-tiles
    int b = bid >> 8, lt = bid & 255;
    int l0 = lt * 8;
    const unsigned* xb32 = (const unsigned*)xbc;
    size_t rb = (size_t)(b * 2048) * 2176;
    for (int cp = threadIdx.x; cp < 2176; cp += 256) {
        int ch = cp << 1;
        const float4* wp = (const float4*)(conv_w + ch * 4);
        float4 wA = wp[0], wB = wp[1];
        float bcA = conv_b[ch], bcB = conv_b[ch + 1];
        float h0A = 0.f, h1A = 0.f, h2A = 0.f, h0B = 0.f, h1B = 0.f, h2B = 0.f;
        if (l0 >= 3) unpack2(xb32[rb + (size_t)(l0 - 3) * 2176 + cp], h0A, h0B);
        if (l0 >= 2) unpack2(xb32[rb + (size_t)(l0 - 2) * 2176 + cp], h1A, h1B);
        if (l0 >= 1) unpack2(xb32[rb + (size_t)(l0 - 1) * 2176 + cp], h2A, h2B);
        #pragma unroll
        for (int i = 0; i < 8; i++) {
            int l = l0 + i;
            float xcA, xcB;
            unpack2(xb32[rb + (size_t)l * 2176 + cp], xcA, xcB);
            float aA = bcA + wA.x * h0A + wA.y * h1A + wA.z * h2A + wA.w * xcA;
            float aB = bcB + wB.x * h0B + wB.y * h1B + wB.z * h2B + wB.w * xcB;
            float vA = aA / (1.f + __expf(-aA));   // silu
            float vB = aB / (1.f + __expf(-aB));
            int row = b * 2048 + l;
            unsigned pk = (unsigned)f2bf(vA) | ((unsigned)f2bf(vB) << 16);
            if (ch < 4096) {
                ((unsigned*)x)[(size_t)row * 2048 + cp] = pk;
            } else if (ch < 4224) {
                ((unsigned*)Bo)[(size_t)row * 64 + (cp - 2048)] = pk;
            } else {
                ((unsigned*)Co)[(size_t)row * 64 + (cp - 2112)] = pk;
            }
            h0A = h1A; h1A = h2A; h2A = xcA;
            h0B = h1B; h1B = h2B; h2B = xcB;
        }
    }
}

// ---------------- per-chunk cumsum of A*dt + chunk totals ----------------
__global__ void k_dtprep(const float* __restrict__ dtq, const float* __restrict__ A_log,
                         float* __restrict__ acum, float* __restrict__ Tc) {
    int bc = blockIdx.x;     // b*32 + c
    int h = threadIdx.x;     // 64 threads
    float A = -__expf(A_log[h]);
    float s = 0.f;
    #pragma unroll
    for (int l = 0; l < 64; l++) {
        int row = bc * 64 + l;
        s += A * dtq[row * 64 + h];
        acum[(size_t)row * 64 + h] = s;
    }
    int b = bc >> 5, c = bc & 31;
    Tc[(b * 64 + h) * 32 + c] = s;
}

// ---------------- G = C * B^T per (b,c); 256 blocks (16 l-rows each) ----------------
__global__ __launch_bounds__(256) void k_G(const u16* __restrict__ Bo, const u16* __restrict__ Co,
                                           float* __restrict__ G) {
    int bc = blockIdx.x;
    int lq = blockIdx.y;             // 0..3, 16 l-rows per block
    __shared__ float BsT[128][68];   // [n][s]
    __shared__ float Cs[16][132];    // [l][n]
    int t = threadIdx.x;
    for (int idx = t; idx < 64 * 128; idx += 256) {
        int r = idx >> 7, n = idx & 127;
        BsT[n][r] = b2f(Bo[(size_t)(bc * 64 + r) * 128 + n]);
    }
    for (int idx = t; idx < 16 * 128; idx += 256) {
        int r = idx >> 7, n = idx & 127;
        Cs[r][n] = b2f(Co[(size_t)(bc * 64 + lq * 16 + r) * 128 + n]);
    }
    __syncthreads();
    int lr = t >> 4, sq = t & 15;    // l-row 0..15, s-quad 0..15 (4 s each)
    int l = lq * 16 + lr;
    float a[4] = {0.f, 0.f, 0.f, 0.f};
    for (int n = 0; n < 128; n++) {
        float cv = Cs[lr][n];
        const float4* bp = (const float4*)&BsT[n][sq * 4];
        float4 b0 = bp[0];
        a[0] += cv * b0.x; a[1] += cv * b0.y; a[2] += cv * b0.z; a[3] += cv * b0.w;
    }
    size_t gb = ((size_t)bc * 64 + l) * 64 + sq * 4;
    #pragma unroll
    for (int i = 0; i < 4; i++) G[gb + i] = a[i];
}

// ---------------- Y_diag + chunk states per (b,c,h), MFMA ----------------
__global__ __launch_bounds__(256) void k_diag(
    const u16* __restrict__ xb, const u16* __restrict__ Bo,
    const float* __restrict__ G, const float* __restrict__ acum,
    const float* __restrict__ dtq,
    u16* __restrict__ y, u16* __restrict__ cs) {
    int bc = blockIdx.x, h = blockIdx.y;
    __shared__ u16 XT[4096];    // [p][s] = x[s][p]*dt[s]
    __shared__ u16 Pl[4096];    // [l][s]
    __shared__ u16 BTd[8192];   // [n][l] = B[l][n]*dec[l]
    __shared__ float ac[64], dec[64], dts[64];
    int t = threadIdx.x, w = t >> 6, lane = t & 63;
    if (t < 64) {
        ac[t] = acum[(size_t)(bc * 64 + t) * 64 + h];
        dts[t] = dtq[(size_t)(bc * 64 + t) * 64 + h];
    }
    __syncthreads();
    if (t < 64) dec[t] = __expf(ac[63] - ac[t]);
    for (int idx = t; idx < 4096; idx += 256) {
        int s = idx >> 6, p = idx & 63;
        float v = b2f(xb[(size_t)(bc * 64 + s) * 4096 + h * 64 + p]) * dts[s];
        XT[(p << 6) + (s ^ ((p & 7) << 3))] = f2bf(v);
    }
    for (int idx = t; idx < 4096; idx += 256) {
        int l = idx >> 6, s = idx & 63;
        float v = (s <= l) ? __expf(ac[l] - ac[s]) * G[((size_t)bc * 64 + l) * 64 + s] : 0.f;
        Pl[(l << 6) + (s ^ ((l & 7) << 3))] = f2bf(v);
    }
    __syncthreads();                     // dec ready
    for (int idx = t; idx < 8192; idx += 256) {
        int l = idx >> 7, n = idx & 127;
        float v = b2f(Bo[(size_t)(bc * 64 + l) * 128 + n]) * dec[l];
        BTd[(n << 6) + (l ^ ((n & 7) << 3))] = f2bf(v);
    }
    __syncthreads();
    // ---- Y_diag: wave w owns l-rows [16w,16w+16); 4 p-tiles; K=64
    {
        floatx4 accY[4];
        #pragma unroll
        for (int ni = 0; ni < 4; ni++) accY[ni] = (floatx4){0.f, 0.f, 0.f, 0.f};
        int row = (w << 4) + (lane & 15);
        #pragma unroll
        for (int ks = 0; ks < 2; ks++) {
            int k = (ks << 5) + ((lane >> 4) << 3);
            int kx = k ^ ((row & 7) << 3);
            bhalf8 af = *(const bhalf8*)(Pl + (row << 6) + kx);
            #pragma unroll
            for (int ni = 0; ni < 4; ni++) {
                int pr = (ni << 4) + (lane & 15);
                bhalf8 bf = *(const bhalf8*)(XT + (pr << 6) + kx);
                accY[ni] = __builtin_amdgcn_mfma_f32_16x16x32_bf16(af, bf, accY[ni], 0, 0, 0);
            }
        }
        #pragma unroll
        for (int ni = 0; ni < 4; ni++) {
            int col = (ni << 4) + (lane & 15);
            #pragma unroll
            for (int r = 0; r < 4; r++) {
                int l = (w << 4) + ((lane >> 4) << 2) + r;
                y[(size_t)(bc * 64 + l) * 4096 + h * 64 + col] = f2bf(accY[ni][r]);
            }
        }
    }
    // ---- chunk state: wave w owns p-rows [16w,16w+16); 8 n-tiles; K=64
    {
        floatx4 accS[8];
        #pragma unroll
        for (int ni = 0; ni < 8; ni++) accS[ni] = (floatx4){0.f, 0.f, 0.f, 0.f};
        int prow = (w << 4) + (lane & 15);
        #pragma unroll
        for (int ks = 0; ks < 2; ks++) {
            int k = (ks << 5) + ((lane >> 4) << 3);
            int kx = k ^ ((prow & 7) << 3);
            bhalf8 af = *(const bhalf8*)(XT + (prow << 6) + kx);
            #pragma unroll
            for (int ni = 0; ni < 8; ni++) {
                int nr = (ni << 4) + (lane & 15);
                bhalf8 bf = *(const bhalf8*)(BTd + (nr << 6) + kx);
                accS[ni] = __builtin_amdgcn_mfma_f32_16x16x32_bf16(af, bf, accS[ni], 0, 0, 0);
            }
        }
        #pragma unroll
        for (int ni = 0; ni < 8; ni++) {
            int n = (ni << 4) + (lane & 15);
            #pragma unroll
            for (int r = 0; r < 4; r++) {
                int p = (w << 4) + ((lane >> 4) << 2) + r;
                cs[((size_t)(bc * 64 + h) * 64 + p) * 128 + n] = f2bf(accS[ni][r]);
            }
        }
    }
}

// ---------------- in-place chunk-prefix scan over c (bf16 storage, fp32 recur) ----------------
__global__ __launch_bounds__(256) void k_scan(u16* __restrict__ cs, const float* __restrict__ Tc) {
    int bid = blockIdx.x;            // 2*64*32 = 4096
    int bh = bid >> 5, pb = bid & 31;
    int b = bh >> 6, h = bh & 63;
    int pn = pb * 256 + threadIdx.x; // 0..8191
    const float* Tp = Tc + bh * 32;
    size_t stride = (size_t)64 * 8192;
    size_t base = (((size_t)(b * 32) * 64) + h) * 8192 + pn;
    float v[32];
    #pragma unroll
    for (int c = 0; c < 32; c++) v[c] = b2f(cs[base + (size_t)c * stride]);
    float P = 0.f;
    #pragma unroll
    for (int c = 0; c < 32; c++) {
        float tmp = v[c];
        cs[base + (size_t)c * stride] = f2bf(P);
        P = __expf(Tp[c]) * P + tmp;
    }
}

// ---------------- Y_off: y += od[l] * C @ S^T  (MFMA, bf16 RMW; 2 h/block) ----------------
__global__ __launch_bounds__(256) void k_yoff(
    const u16* __restrict__ Co, const u16* __restrict__ cs,
    const float* __restrict__ acum, u16* __restrict__ y) {
    int bc = blockIdx.x;
    int h0 = blockIdx.y << 1;          // handles h0, h0+1 (C staged once)
    __shared__ u16 Cl[8192];   // [l][n], 128-col rows: swz ^((row&15)<<3)
    __shared__ u16 Sl[2][8192];
    __shared__ float od[2][64];
    int t = threadIdx.x, w = t >> 6, lane = t & 63;
    for (int idx = t; idx < 8192; idx += 256) {
        int l = idx >> 7, n = idx & 127;
        Cl[(l << 7) + (n ^ ((l & 15) << 3))] = Co[(size_t)(bc * 64 + l) * 128 + n];
    }
    #pragma unroll
    for (int j = 0; j < 2; j++) {
        size_t pbase = ((size_t)bc * 64 + (h0 + j)) * 8192;
        for (int idx = t; idx < 8192; idx += 256) {
            int p = idx >> 7, n = idx & 127;
            Sl[j][(p << 7) + (n ^ ((p & 15) << 3))] = cs[pbase + idx];
        }
    }
    if (t < 128) {
        int j = t >> 6, l = t & 63;
        od[j][l] = __expf(acum[(size_t)(bc * 64 + l) * 64 + h0 + j]);
    }
    __syncthreads();
    int lrow = (w << 4) + (lane & 15);
    #pragma unroll
    for (int j = 0; j < 2; j++) {
        floatx4 acc[4];
        #pragma unroll
        for (int ni = 0; ni < 4; ni++) acc[ni] = (floatx4){0.f, 0.f, 0.f, 0.f};
        #pragma unroll
        for (int ks = 0; ks < 4; ks++) {
            int k = (ks << 5) + ((lane >> 4) << 3);
            int kx = k ^ ((lrow & 15) << 3);
            bhalf8 af = *(const bhalf8*)(Cl + (lrow << 7) + kx);
            #pragma unroll
            for (int ni = 0; ni < 4; ni++) {
                int pr = (ni << 4) + (lane & 15);
                bhalf8 bf = *(const bhalf8*)(Sl[j] + (pr << 7) + kx);
                acc[ni] = __builtin_amdgcn_mfma_f32_16x16x32_bf16(af, bf, acc[ni], 0, 0, 0);
            }
        }
        #pragma unroll
        for (int ni = 0; ni < 4; ni++) {
            int col = (ni << 4) + (lane & 15);
            #pragma unroll
            for (int r = 0; r < 4; r++) {
                int l = (w << 4) + ((lane >> 4) << 2) + r;
                size_t yi = (size_t)(bc * 64 + l) * 4096 + (h0 + j) * 64 + col;
                y[yi] = f2bf(b2f(y[yi]) + od[j][l] * acc[ni][r]);
            }
        }
    }
}

// ---------------- gating (silu(z)) + D skip + RMSNorm -> bf16 ----------------
__global__ __launch_bounds__(256) void k_norm(
    const u16* __restrict__ y, const u16* __restrict__ x, const u16* __restrict__ z,
    const float* __restrict__ D_param, const float* __restrict__ norm_w,
    u16* __restrict__ ynorm) {
    int row = blockIdx.x;
    int t = threadIdx.x;
    size_t base = (size_t)row * 4096 + (size_t)t * 16;
    float yv[16], xf[16], zf[16];
    {
        uint4 a = ((const uint4*)(y + base))[0];
        uint4 b = ((const uint4*)(y + base))[1];
        unpack2(a.x, yv[0], yv[1]); unpack2(a.y, yv[2], yv[3]);
        unpack2(a.z, yv[4], yv[5]); unpack2(a.w, yv[6], yv[7]);
        unpack2(b.x, yv[8], yv[9]); unpack2(b.y, yv[10], yv[11]);
        unpack2(b.z, yv[12], yv[13]); unpack2(b.w, yv[14], yv[15]);
    }
    {
        uint4 a = ((const uint4*)(x + base))[0];
        uint4 b = ((const uint4*)(x + base))[1];
        unpack2(a.x, xf[0], xf[1]); unpack2(a.y, xf[2], xf[3]);
        unpack2(a.z, xf[4], xf[5]); unpack2(a.w, xf[6], xf[7]);
        unpack2(b.x, xf[8], xf[9]); unpack2(b.y, xf[10], xf[11]);
        unpack2(b.z, xf[12], xf[13]); unpack2(b.w, xf[14], xf[15]);
    }
    {
        uint4 a = ((const uint4*)(z + base))[0];
        uint4 b = ((const uint4*)(z + base))[1];
        unpack2(a.x, zf[0], zf[1]); unpack2(a.y, zf[2], zf[3]);
        unpack2(a.z, zf[4], zf[5]); unpack2(a.w, zf[6], zf[7]);
        unpack2(b.x, zf[8], zf[9]); unpack2(b.y, zf[10], zf[11]);
        unpack2(b.z, zf[12], zf[13]); unpack2(b.w, zf[14], zf[15]);
    }
    float D = D_param[t >> 2];
    float vals[16], ss = 0.f;
    #pragma unroll
    for (int j = 0; j < 16; j++) {
        float v = yv[j] + xf[j] * D;
        float zz = zf[j];
        float yf = v * (zz / (1.f + __expf(-zz)));
        vals[j] = yf;
        ss += yf * yf;
    }
    #pragma unroll
    for (int o = 32; o > 0; o >>= 1) ss += __shfl_down(ss, o, 64);
    __shared__ float red[4];
    if ((t & 63) == 0) red[t >> 6] = ss;
    __syncthreads();
    float tot = red[0] + red[1] + red[2] + red[3];
    float rr = rsqrtf(tot * (1.f / 4096.f) + 1e-5f);
    unsigned o32[8];
    #pragma unroll
    for (int j = 0; j < 8; j++) {
        float lo = vals[2 * j] * rr * norm_w[t * 16 + 2 * j];
        float hi = vals[2 * j + 1] * rr * norm_w[t * 16 + 2 * j + 1];
        o32[j] = (unsigned)f2bf(lo) | ((unsigned)f2bf(hi) << 16);
    }
    uint4 w0, w1;
    w0.x = o32[0]; w0.y = o32[1]; w0.z = o32[2]; w0.w = o32[3];
    w1.x = o32[4]; w1.y = o32[5]; w1.z = o32[6]; w1.w = o32[7];
    ((uint4*)(ynorm + base))[0] = w0;
    ((uint4*)(ynorm + base))[1] = w1;
}

// ---------------- launch ----------------
extern "C" void kernel_launch(void* const* d_in, const int* in_sizes, int n_in,
                              void* d_out, int out_size, void* d_ws, size_t ws_size,
                              hipStream_t stream) {
    const float* u       = (const float*)d_in[0];
    const float* W_in    = (const float*)d_in[1];
    const float* conv_w  = (const float*)d_in[2];
    const float* conv_b  = (const float*)d_in[3];
    const float* dt_bias = (const float*)d_in[4];
    const float* A_log   = (const float*)d_in[5];
    const float* D_param = (const float*)d_in[6];
    const float* norm_w  = (const float*)d_in[7];
    const float* W_out   = (const float*)d_in[8];
    float* out = (float*)d_out;

    // ---- workspace budget (lifetime-aliased) ----
    const size_t REGION = (size_t)134217728;
    size_t need = REGION
                + (size_t)33554432   // zb
                + (size_t)33554432   // xb
                + (size_t)1048576    // Bo
                + (size_t)1048576    // Co
                + (size_t)1048576    // acum
                + (size_t)16384      // Tc
                + (size_t)1048576    // G
                + (size_t)1048576    // dtq
                + (size_t)33554432;  // yb
    if (ws_size < need) return;      // diagnostic: clean absmax fail, no fault

    char* ws = (char*)d_ws;
    // transient region overlays
    u16*   ubf   = (u16*)(ws);
    u16*   WinT  = (u16*)(ws + 16777216);
    u16*   xbc   = (u16*)(ws + 16777216 + 35651584);
    u16*   cs    = (u16*)(ws);
    u16*   WoutT = (u16*)(ws);
    u16*   ynorm = (u16*)(ws + 16777216);
    // persistent
    char* p = ws + REGION;
    u16*   zb    = (u16*)p;            p += 33554432;
    u16*   xb    = (u16*)p;            p += 33554432;
    u16*   Bo    = (u16*)p;            p += 1048576;
    u16*   Co    = (u16*)p;            p += 1048576;
    float* acum  = (float*)p;          p += 1048576;
    float* Tc    = (float*)p;          p += 16384;
    float* G     = (float*)p;          p += 1048576;
    float* dtq   = (float*)p;          p += 1048576;
    u16*   yb    = (u16*)p;            p += 33554432;

    // 1. u -> bf16
    k_f2b4<<<8192, 256, 0, stream>>>(u, ubf, 4096 * 2048 / 4);
    // 2. W_in -> bf16 transposed, padded to 8576 rows (67 x 128-tiles)
    k_transpose_f2b<<<dim3(268, 64), dim3(32, 8), 0, stream>>>(W_in, WinT, 2048, 8512);
    // 3. in_proj GEMM (BK=32 dbuf, 5 blocks/CU) + split/softplus epilogue
    gemm_bt<1><<<dim3(67, 32), 256, 0, stream>>>(ubf, WinT, 4096, 8576, 2048,
                                                 nullptr, zb, xbc, dtq, dt_bias);
    // 4. conv + silu + split (x, B, C); 8-row register-ring, 2 ch/thread
    k_conv<<<512, 256, 0, stream>>>(xbc, conv_w, conv_b, xb, Bo, Co);
    // 5. cumsum(A*dt) per chunk + chunk totals
    k_dtprep<<<64, 64, 0, stream>>>(dtq, A_log, acum, Tc);
    // 6. G = C B^T (256 blocks)
    k_G<<<dim3(64, 4), 256, 0, stream>>>(Bo, Co, G);
    // 7. Y_diag + chunk states, MFMA  (xbc dead -> cs overlays region)
    k_diag<<<dim3(64, 64), 256, 0, stream>>>(xb, Bo, G, acum, dtq, yb, cs);
    // 8. chunk-prefix scan (in place, bf16)
    k_scan<<<4096, 256, 0, stream>>>(cs, Tc);
    // 9. Y_off accumulate into yb (MFMA, bf16 RMW; 2 h per block)
    k_yoff<<<dim3(64, 32), 256, 0, stream>>>(Co, cs, acum, yb);
    // 10. W_out -> bf16 transposed (cs dead -> WoutT overlays region)
    k_transpose_f2b<<<dim3(64, 128), dim3(32, 8), 0, stream>>>(W_out, WoutT, 4096, 2048);
    // 11. gating + D skip + RMSNorm -> bf16
    k_norm<<<4096, 256, 0, stream>>>(yb, xb, zb, D_param, norm_w, ynorm);
    // 12. out_proj GEMM (BK=32 dbuf) -> fp32 out
    gemm_bt<0><<<dim3(16, 32), 256, 0, stream>>>(ynorm, WoutT, 4096, 2048, 4096,
                                                 out, nullptr, nullptr, nullptr, nullptr);
    (void)in_sizes; (void)n_in; (void)out_size;
}